// Round 9
// baseline (878.879 us; speedup 1.0000x reference)
//
#include <hip/hip_runtime.h>
#include <hip/hip_fp16.h>

typedef unsigned int uint;
typedef unsigned short ushort;
typedef __attribute__((ext_vector_type(8))) short short8;   // 8 bf16 in 4 VGPRs
typedef __attribute__((ext_vector_type(4))) float f32x4;
typedef __attribute__((ext_vector_type(2))) float f32x2;    // v_pk_fma_f32

#define N_NODES 50000
#define N_EDGES 800000
#define ETOT    (2 * N_EDGES + N_NODES)   // 1,650,000
#define NG      64
#define NBKT    256                       // coarse buckets (dst>>8), 196 used
#define MAXB    10240                     // EST staging capacity per bucket
#define EPB     8192                      // edges per bucket_k block
#define NBK1    ((ETOT + EPB - 1) / EPB)  // 202
#define AROW    640                       // MEGA row stride in shorts (1280 B)

__device__ __forceinline__ short f2bf(float f) {   // RNE float->bf16
  uint u = __float_as_uint(f);
  u += 0x7fffu + ((u >> 16) & 1u);
  return (short)(u >> 16);
}
__device__ __forceinline__ float bf2f(short s) {
  return __uint_as_float(((uint)(ushort)s) << 16);
}
__device__ __forceinline__ uint packbf(float a, float b) {
  return (uint)(ushort)f2bf(a) | ((uint)(ushort)f2bf(b) << 16);
}
__device__ __forceinline__ uint pkh2(float a, float b) {   // 2xfp16 pack
  __half2 h = __floats2half2_rn(a, b);
  return *(uint*)&h;
}
__device__ __forceinline__ float2 uph2(uint u) {           // 2xfp16 unpack
  __half2 h = *(__half2*)&u;
  return __half22float2(h);
}

// ---------------------------------------------------------------------------
// K1: bucket edges by dst>>8 into padded staging. LDS histogram; one global
// atomic per (block,bin). Entry: src(16b) | dst_low(8b)<<16 | selfloop<<24
// ---------------------------------------------------------------------------
__global__ __launch_bounds__(256) void bucket_k(const int* __restrict__ ei,
                                                int* __restrict__ gfill,
                                                uint* __restrict__ est) {
  __shared__ int hist[NBKT];
  __shared__ int cursor[NBKT];
  const int tid = threadIdx.x;
  hist[tid] = 0;
  __syncthreads();
  const int e0 = blockIdx.x * EPB;
#pragma unroll 4
  for (int i = 0; i < EPB / 256; ++i) {
    int e = e0 + i * 256 + tid;
    if (e < ETOT) {
      int d;
      if (e < N_EDGES)          d = ei[N_EDGES + e];
      else if (e < 2 * N_EDGES) d = ei[e - N_EDGES];
      else                      d = e - 2 * N_EDGES;
      atomicAdd(&hist[d >> 8], 1);
    }
  }
  __syncthreads();
  cursor[tid] = atomicAdd(&gfill[tid], hist[tid]);
  __syncthreads();
#pragma unroll 4
  for (int i = 0; i < EPB / 256; ++i) {
    int e = e0 + i * 256 + tid;
    if (e < ETOT) {
      int s, d, fl = 0;
      if (e < N_EDGES)          { s = ei[e];           d = ei[N_EDGES + e]; }
      else if (e < 2 * N_EDGES) { s = ei[e];           d = ei[e - N_EDGES]; }
      else                      { s = e - 2 * N_EDGES; d = s; fl = 1; }
      int b = d >> 8;
      int slot = atomicAdd(&cursor[b], 1);
      est[(size_t)b * MAXB + slot] = (uint)s | ((uint)(d & 255) << 16) | ((uint)fl << 24);
    }
  }
}

// Exclusive scan of the 256 bucket counts -> dense bucket bases
__global__ __launch_bounds__(256) void bktscan_k(const int* __restrict__ gfill,
                                                 int* __restrict__ bktbase) {
  __shared__ int wsum[4];
  int tid = threadIdx.x, lane = tid & 63, wid = tid >> 6;
  int v = gfill[tid];
  int x = v;
#pragma unroll
  for (int d = 1; d < 64; d <<= 1) {
    int t = __shfl_up(x, d, 64);
    if (lane >= d) x += t;
  }
  if (lane == 63) wsum[wid] = x;
  __syncthreads();
  int woff = 0;
#pragma unroll
  for (int j = 0; j < 4; ++j) if (j < wid) woff += wsum[j];
  bktbase[tid] = woff + x - v;
}

// ---------------------------------------------------------------------------
// K2: per-bucket regroup by dst low byte -> DENSE CSR + dinv
// ---------------------------------------------------------------------------
__global__ __launch_bounds__(256) void group_k(const int* __restrict__ gfill,
                                               const int* __restrict__ bktbase,
                                               const uint* __restrict__ est,
                                               const float* __restrict__ ewp,
                                               int* __restrict__ csrc,
                                               int* __restrict__ rbeg,
                                               int* __restrict__ rend,
                                               float* __restrict__ dinv) {
  __shared__ int hist[NBKT];
  __shared__ int cursor[NBKT];
  __shared__ int wsum[4];
  const int b = blockIdx.x;
  const int tid = threadIdx.x;
  const int cnt = gfill[b];
  const int gb = bktbase[b];
  hist[tid] = 0;
  __syncthreads();
  const uint* basep = est + (size_t)b * MAXB;
  for (int i = tid; i < cnt; i += 256)
    atomicAdd(&hist[(basep[i] >> 16) & 255], 1);
  __syncthreads();
  int v = hist[tid];
  int lane = tid & 63, wid = tid >> 6;
  int x = v;
#pragma unroll
  for (int d = 1; d < 64; d <<= 1) {
    int t = __shfl_up(x, d, 64);
    if (lane >= d) x += t;
  }
  if (lane == 63) wsum[wid] = x;
  __syncthreads();
  int woff = 0;
#pragma unroll
  for (int j = 0; j < 4; ++j) if (j < wid) woff += wsum[j];
  int excl = woff + x - v;
  cursor[tid] = excl;
  int node = b * 256 + tid;
  if (node < N_NODES) {
    rbeg[node] = gb + excl;
    rend[node] = gb + excl + v;
    float deg = ewp[0] * (float)(v - 1) + 2.0f;
    dinv[node] = (deg > 0.f) ? rsqrtf(deg) : 0.f;
  }
  __syncthreads();
  for (int i = tid; i < cnt; i += 256) {
    uint en = basep[i];
    int dlow = (en >> 16) & 255;
    int slot = atomicAdd(&cursor[dlow], 1);
    csrc[gb + slot] = (int)(en & 0xffffu) | (int)((en >> 24) << 31);
  }
}

// Graph sizes via binary search on sorted batch
__global__ __launch_bounds__(128) void gcnt_k(const int* __restrict__ batch,
                                              int* __restrict__ gcnt) {
  __shared__ int lb[NG + 1];
  int g = threadIdx.x;
  if (g <= NG) {
    int lo = 0, hi = N_NODES;
    while (lo < hi) {
      int mid = (lo + hi) >> 1;
      if (batch[mid] < g) lo = mid + 1; else hi = mid;
    }
    lb[g] = lo;
  }
  __syncthreads();
  if (g < NG) gcnt[g] = lb[g + 1] - lb[g];
}

// ---------------------------------------------------------------------------
// x fp32 -> bf16
// ---------------------------------------------------------------------------
__global__ __launch_bounds__(256) void convx_k(const float* __restrict__ x,
                                               short* __restrict__ xb) {
  int i = (blockIdx.x * 256 + threadIdx.x) * 4;
  float4 v = *(const float4*)(x + i);
  *(uint2*)(xb + i) = make_uint2(packbf(v.x, v.y), packbf(v.z, v.w));
}

// ---------------------------------------------------------------------------
// Weight prep. All source mats are [128(k) x ncol] fp32.
// ---------------------------------------------------------------------------
__global__ __launch_bounds__(256) void prep_k(const float* __restrict__ w_in1,
                                              const float* __restrict__ w_in2,
                                              const float* __restrict__ gat_w,
                                              const float* __restrict__ gcn_w,
                                              const float* __restrict__ skip_w,
                                              const float* __restrict__ w_h1,
                                              const float* __restrict__ w_h2,
                                              short* __restrict__ WT0,
                                              short* __restrict__ WT1,
                                              short* __restrict__ WTL2,
                                              short* __restrict__ WTS,
                                              short* __restrict__ WTH1,
                                              short* __restrict__ WTH2) {
  int mat = blockIdx.x >> 2, qr = blockIdx.x & 3;
  const float* src; short* dst; int ncol = 128, dstride = 128, doff = 0;
  switch (mat) {
    case 0:  src = w_in1; dst = WT0; break;
    case 1:  src = w_in2; dst = WT1; break;
    case 2: case 3: case 4:
      src = gat_w + (size_t)(mat - 2) * 16384; dst = WTL2 + (size_t)(mat - 2) * 32768;
      dstride = 256; break;
    case 5: case 6: case 7:
      src = gcn_w + (size_t)(mat - 5) * 16384; dst = WTL2 + (size_t)(mat - 5) * 32768;
      dstride = 256; doff = 128; break;
    case 8:  src = skip_w;             dst = WTS;         break;
    case 9:  src = skip_w + 2 * 16384; dst = WTS + 16384; break;
    case 10: src = w_h1; dst = WTH1; break;
    default: src = w_h2; dst = WTH2; ncol = 64; break;
  }
  int total = 128 * ncol, chunk = total / 4;
  for (int d = qr * chunk + threadIdx.x; d < (qr + 1) * chunk; d += 256) {
    int col = d >> 7, k = d & 127;
    dst[col * dstride + doff + k] = f2bf(src[k * ncol + col]);
  }
}

// ---------------------------------------------------------------------------
// Attention projection + bias sums (ATTW rows 8..15 zero)
// ---------------------------------------------------------------------------
__global__ __launch_bounds__(256) void attprep_k(const float* __restrict__ gat_w,
                                                 const float* __restrict__ asrc,
                                                 const float* __restrict__ adst,
                                                 const float* __restrict__ gat_b,
                                                 const float* __restrict__ gcn_b,
                                                 short* __restrict__ ATTW,
                                                 float* __restrict__ BSUM) {
  const int tid = threadIdx.x;
  for (int t = tid; t < 3072; t += 256) {          // 3 layers x 8 rows x 128 k
    int l = t >> 10, rem = t & 1023;
    int r = rem >> 7, k = rem & 127;
    int hd = r & 3;
    const float* av = (r < 4) ? (asrc + l * 128 + hd * 32) : (adst + l * 128 + hd * 32);
    const float* wrow = gat_w + (size_t)l * 16384 + k * 128 + hd * 32;
    float s = 0.f;
#pragma unroll
    for (int c = 0; c < 32; ++c) s = fmaf(wrow[c], av[c], s);
    ATTW[(size_t)l * 2048 + r * 128 + k] = f2bf(s);
  }
  for (int t = tid; t < 3072; t += 256)            // zero rows 8..15
    ATTW[(size_t)(t >> 10) * 2048 + 1024 + (t & 1023)] = 0;
  for (int t = tid; t < 384; t += 256) {
    int l = t >> 7, c = t & 127;
    BSUM[t] = gat_b[l * 128 + c] + gcn_b[l * 128 + c];
  }
}

// ---------------------------------------------------------------------------
// bf16 MFMA GEMM (K=128). ADD: addsrc is bf16, row stride 128.
// F32OUT -> outf (row stride NCOL).
// ---------------------------------------------------------------------------
template <int NCOL, int RELU, int ADD, int F32OUT>
__global__ __launch_bounds__(256) void bgemm_k(const short* __restrict__ A,
                                               const short* __restrict__ WT,
                                               const float* __restrict__ bias,
                                               const short* __restrict__ addsrc,
                                               short* __restrict__ outb,
                                               float* __restrict__ outf, int M) {
  constexpr int NT = NCOL / 16;
  const int lane = threadIdx.x & 63;
  const int wid = threadIdx.x >> 6;
  const int mbase = blockIdx.x * 64 + wid * 16;
  const int l15 = lane & 15, q = lane >> 4;
  int arow = mbase + l15; if (arow > M - 1) arow = M - 1;
  const short* ap = A + (size_t)arow * 128 + q * 8;
  const short* bp = WT + (size_t)l15 * 128 + q * 8;
  f32x4 acc[NT];
#pragma unroll
  for (int t = 0; t < NT; ++t) acc[t] = (f32x4)0.f;
#pragma unroll
  for (int c = 0; c < 4; ++c) {
    short8 av = *(const short8*)(ap + c * 32);
#pragma unroll
    for (int t = 0; t < NT; ++t) {
      short8 bv = *(const short8*)(bp + (size_t)t * 16 * 128 + c * 32);
      acc[t] = __builtin_amdgcn_mfma_f32_16x16x32_bf16(av, bv, acc[t], 0, 0, 0);
    }
  }
#pragma unroll
  for (int t = 0; t < NT; ++t) {
    int col = t * 16 + l15;
    float bb = bias ? bias[col] : 0.f;
#pragma unroll
    for (int r = 0; r < 4; ++r) {
      int row = mbase + q * 4 + r;
      if (row < M) {
        float v = acc[t][r] + bb;
        if (ADD) v += bf2f(addsrc[(size_t)row * 128 + col]);
        if (RELU) v = v > 0.f ? v : 0.f;
        if (F32OUT) outf[(size_t)row * NCOL + col] = v;
        else        outb[(size_t)row * NCOL + col] = f2bf(v);
      }
    }
  }
}

// ---------------------------------------------------------------------------
// Fused coef + GAT/GCN aggregation, PER-HEAD. One node per wave.
// Row processed in 64-edge chunks:
//   phase1: one edge per lane -> exps/c2/src into LDS uint4 (ds_write_b128)
//   phase2: 2 edges/iter, 32 lanes each, 4 feats/lane; one ds_read_b128 per
//           edge (broadcast within half-wave); accumulation in f32x2 packed FMA.
// Softmax normalization applied in epilogue (den accumulated in phase1).
// A row layout [n][AROW] bf16: [gat_hd0 128][hd1][hd2][hd3][gcn 128].
// sc layout: sc[n*16 + hd] = src score, sc[n*16 + 4 + hd] = dst score.
// ---------------------------------------------------------------------------
__global__ __launch_bounds__(256) void agg_k(const short* __restrict__ h,
                                             const float* __restrict__ sc,
                                             const int* __restrict__ rbeg,
                                             const int* __restrict__ rend,
                                             const int* __restrict__ cs,
                                             const float* __restrict__ dinv,
                                             const float* __restrict__ ewp,
                                             short* __restrict__ A) {
  __shared__ uint4 lco[4][64];       // [wave][edge-in-chunk] {p01,p23,c2|src,0}
  const int n = blockIdx.x * 4 + (threadIdx.x >> 6);
  const int wv = threadIdx.x >> 6;
  const int l = threadIdx.x & 63;
  const int sub = l >> 5;            // which edge of the pair (phase2)
  const int f4 = l & 31;             // feature quad (phase2)
  const float ew0 = ewp[0];
  const float dn = dinv[n];
  const f32x4 sdv = *(const f32x4*)(sc + n * 16 + 4);
  const int beg = rbeg[n], end = rend[n];
  float den[4] = {0.f, 0.f, 0.f, 0.f};
  f32x2 ag[4][2], ac[2];
#pragma unroll
  for (int hd = 0; hd < 4; ++hd) { ag[hd][0] = (f32x2)0.f; ag[hd][1] = (f32x2)0.f; }
  ac[0] = (f32x2)0.f; ac[1] = (f32x2)0.f;

  for (int c0 = beg; c0 < end; c0 += 64) {
    const int nc = min(64, end - c0);
    // ---- phase 1: this lane's edge -> LDS ----
    {
      uint4 w = make_uint4(0u, 0u, 0u, 0u);
      int e = c0 + l;
      if (e < end) {
        int raw = cs[e];
        int s = raw & 0x7fffffff;
        float wt = (raw < 0) ? 2.0f : ew0;
        f32x4 ssv = *(const f32x4*)(sc + (size_t)s * 16);
        float a0 = ssv[0] + sdv[0]; a0 = fmaxf(a0, 0.2f * a0);
        float a1 = ssv[1] + sdv[1]; a1 = fmaxf(a1, 0.2f * a1);
        float a2 = ssv[2] + sdv[2]; a2 = fmaxf(a2, 0.2f * a2);
        float a3 = ssv[3] + sdv[3]; a3 = fmaxf(a3, 0.2f * a3);
        float e0 = __expf(a0), e1 = __expf(a1);
        float e2 = __expf(a2), e3 = __expf(a3);
        den[0] += e0; den[1] += e1; den[2] += e2; den[3] += e3;
        float c2 = dinv[s] * wt * dn;
        __half hc = __float2half(c2);
        w = make_uint4(pkh2(e0, e1), pkh2(e2, e3),
                       (uint)(*(ushort*)&hc) | ((uint)s << 16), 0u);
      }
      lco[wv][l] = w;
    }
    // same wave wrote, same wave reads: no __syncthreads needed (lgkmcnt only)
    // ---- phase 2: aggregate chunk, 2 edges per iteration ----
    const int pairs = (nc + 1) & ~1;
#pragma unroll 2
    for (int j = sub; j < pairs; j += 2) {
      uint4 cw = lco[wv][j];
      int s = (int)(cw.z >> 16);
      float2 p01 = uph2(cw.x);
      float2 p23 = uph2(cw.y);
      ushort hc = (ushort)(cw.z & 0xffffu);
      float c2 = __half2float(*(__half*)&hc);
      uint2 u = *(const uint2*)(h + (size_t)s * 128 + f4 * 4);
      f32x2 va, vb;
      va.x = __uint_as_float(u.x << 16);
      va.y = __uint_as_float(u.x & 0xffff0000u);
      vb.x = __uint_as_float(u.y << 16);
      vb.y = __uint_as_float(u.y & 0xffff0000u);
      f32x2 cc;
      cc.x = p01.x; cc.y = p01.x;
      ag[0][0] += cc * va; ag[0][1] += cc * vb;
      cc.x = p01.y; cc.y = p01.y;
      ag[1][0] += cc * va; ag[1][1] += cc * vb;
      cc.x = p23.x; cc.y = p23.x;
      ag[2][0] += cc * va; ag[2][1] += cc * vb;
      cc.x = p23.y; cc.y = p23.y;
      ag[3][0] += cc * va; ag[3][1] += cc * vb;
      cc.x = c2; cc.y = c2;
      ac[0] += cc * va; ac[1] += cc * vb;
    }
  }

  // reduce denominators across the full wave (phase1 partials live per lane)
#pragma unroll
  for (int off = 1; off < 64; off <<= 1) {
    den[0] += __shfl_xor(den[0], off, 64);
    den[1] += __shfl_xor(den[1], off, 64);
    den[2] += __shfl_xor(den[2], off, 64);
    den[3] += __shfl_xor(den[3], off, 64);
  }
  // reduce aggregates across the two half-waves
#pragma unroll
  for (int hd = 0; hd < 4; ++hd)
#pragma unroll
    for (int i = 0; i < 2; ++i) {
      f32x2 t = ag[hd][i];
      t.x += __shfl_xor(t.x, 32, 64);
      t.y += __shfl_xor(t.y, 32, 64);
      ag[hd][i] = t;
    }
#pragma unroll
  for (int i = 0; i < 2; ++i) {
    f32x2 t = ac[i];
    t.x += __shfl_xor(t.x, 32, 64);
    t.y += __shfl_xor(t.y, 32, 64);
    ac[i] = t;
  }

  float inv[4] = {1.0f / (den[0] + 1e-16f), 1.0f / (den[1] + 1e-16f),
                  1.0f / (den[2] + 1e-16f), 1.0f / (den[3] + 1e-16f)};
  short* base = A + (size_t)n * AROW;
  if (sub == 0) {
#pragma unroll
    for (int hd = 0; hd < 2; ++hd) {
      float iv = inv[hd];
      *(uint2*)(base + hd * 128 + f4 * 4) =
          make_uint2(packbf(ag[hd][0].x * iv, ag[hd][0].y * iv),
                     packbf(ag[hd][1].x * iv, ag[hd][1].y * iv));
    }
    *(uint2*)(base + 512 + f4 * 4) =
        make_uint2(packbf(ac[0].x, ac[0].y), packbf(ac[1].x, ac[1].y));
  } else {
#pragma unroll
    for (int hd = 2; hd < 4; ++hd) {
      float iv = inv[hd];
      *(uint2*)(base + hd * 128 + f4 * 4) =
          make_uint2(packbf(ag[hd][0].x * iv, ag[hd][0].y * iv),
                     packbf(ag[hd][1].x * iv, ag[hd][1].y * iv));
    }
  }
}

// ---------------------------------------------------------------------------
// Head-structured projection; output GB is bf16 occupying the first 128 shorts
// of each MEGA row (stride AROW) — same-row alias, reads precede writes within
// the owning wave; no __restrict__ on A/GB keeps program order.
// ---------------------------------------------------------------------------
__global__ __launch_bounds__(256) void aggproj_k(const short* A,
                                                 const short* __restrict__ WT,
                                                 const float* __restrict__ bsum,
                                                 short* GB, int M) {
  const int lane = threadIdx.x & 63;
  const int wid = threadIdx.x >> 6;
  const int mbase = blockIdx.x * 64 + wid * 16;
  const int l15 = lane & 15, q = lane >> 4;
  int arow = mbase + l15; if (arow > M - 1) arow = M - 1;
  const short* ap = A + (size_t)arow * AROW + q * 8;
  const short* bp = WT + (size_t)l15 * 256 + q * 8;
  f32x4 acc[8];
#pragma unroll
  for (int t = 0; t < 8; ++t) acc[t] = (f32x4)0.f;
  short8 avg[4];
#pragma unroll
  for (int c = 0; c < 4; ++c) avg[c] = *(const short8*)(ap + 512 + c * 32);
#pragma unroll
  for (int hd = 0; hd < 4; ++hd) {
    short8 avh[4];
#pragma unroll
    for (int c = 0; c < 4; ++c) avh[c] = *(const short8*)(ap + hd * 128 + c * 32);
#pragma unroll
    for (int tt = 0; tt < 2; ++tt) {
      int t = hd * 2 + tt;
      const short* bpt = bp + (size_t)t * 16 * 256;
#pragma unroll
      for (int c = 0; c < 4; ++c) {
        short8 bv = *(const short8*)(bpt + c * 32);
        acc[t] = __builtin_amdgcn_mfma_f32_16x16x32_bf16(avh[c], bv, acc[t], 0, 0, 0);
      }
#pragma unroll
      for (int c = 0; c < 4; ++c) {
        short8 bv = *(const short8*)(bpt + 128 + c * 32);
        acc[t] = __builtin_amdgcn_mfma_f32_16x16x32_bf16(avg[c], bv, acc[t], 0, 0, 0);
      }
    }
  }
#pragma unroll
  for (int t = 0; t < 8; ++t) {
    int col = t * 16 + l15;
    float bb = bsum[col];
#pragma unroll
    for (int r = 0; r < 4; ++r) {
      int row = mbase + q * 4 + r;
      if (row < M) GB[(size_t)row * AROW + col] = f2bf(acc[t][r] + bb);
    }
  }
}

// ---------------------------------------------------------------------------
// GraphNorm stats on GB (bf16, row stride AROW). Thread = feature pair.
// ---------------------------------------------------------------------------
__global__ __launch_bounds__(256) void stats_k(const short* __restrict__ gb,
                                               const int* __restrict__ batch,
                                               float* __restrict__ gsum) {
  int c2 = threadIdx.x & 63;          // feature pair: 2c2, 2c2+1
  int qr = threadIdx.x >> 6;          // row group
  int nb = blockIdx.x * 16;
  float s0 = 0.f, s1 = 0.f, q0 = 0.f, q1 = 0.f;
  int curb = -1;
  for (int i = qr; i < 16; i += 4) {
    int n = nb + i;
    int b = batch[n];
    if (b != curb) {
      if (curb >= 0) {
        atomicAdd(&gsum[curb * 256 + 2 * c2], s0);
        atomicAdd(&gsum[curb * 256 + 2 * c2 + 1], s1);
        atomicAdd(&gsum[curb * 256 + 128 + 2 * c2], q0);
        atomicAdd(&gsum[curb * 256 + 128 + 2 * c2 + 1], q1);
      }
      curb = b; s0 = s1 = q0 = q1 = 0.f;
    }
    uint u = *(const uint*)(gb + (size_t)n * AROW + 2 * c2);
    float v0 = __uint_as_float(u << 16);
    float v1 = __uint_as_float(u & 0xffff0000u);
    s0 += v0; q0 = fmaf(v0, v0, q0);
    s1 += v1; q1 = fmaf(v1, v1, q1);
  }
  if (curb >= 0) {
    atomicAdd(&gsum[curb * 256 + 2 * c2], s0);
    atomicAdd(&gsum[curb * 256 + 2 * c2 + 1], s1);
    atomicAdd(&gsum[curb * 256 + 128 + 2 * c2], q0);
    atomicAdd(&gsum[curb * 256 + 128 + 2 * c2 + 1], q1);
  }
}

// GraphNorm + ELU: GB bf16 (stride AROW) -> outb bf16 (stride 128)
__global__ __launch_bounds__(256) void normelu_k(const short* __restrict__ gb,
                                                 const int* __restrict__ batch,
                                                 const float* __restrict__ gsum,
                                                 const int* __restrict__ gcnt,
                                                 const float* __restrict__ nw,
                                                 const float* __restrict__ nb_,
                                                 const float* __restrict__ nms,
                                                 short* __restrict__ outb) {
  int n = blockIdx.x * 4 + (threadIdx.x >> 6);
  int c2 = threadIdx.x & 63;
  int b = batch[n];
  float cntf = fmaxf((float)gcnt[b], 1.0f);
  float cinv = 1.0f / cntf;
  uint u = *(const uint*)(gb + (size_t)n * AROW + 2 * c2);
  float o[2];
#pragma unroll
  for (int k = 0; k < 2; ++k) {
    int c = 2 * c2 + k;
    float mean = gsum[b * 256 + c] * cinv;
    float msq  = gsum[b * 256 + 128 + c] * cinv;
    float ms = nms[c];
    float var = fmaxf(msq - (2.0f * ms - ms * ms) * mean * mean, 0.f);
    float v = (k == 0) ? __uint_as_float(u << 16) : __uint_as_float(u & 0xffff0000u);
    float t = (v - mean * ms) * rsqrtf(var + 1e-5f) * nw[c] + nb_[c];
    o[k] = (t > 0.f) ? t : (__expf(t) - 1.0f);
  }
  *(uint*)(outb + (size_t)n * 128 + 2 * c2) = packbf(o[0], o[1]);
}

// Final head: sigmoid(<p2[n,:64], w3> + b3), p2 bf16
__global__ __launch_bounds__(256) void head3_k(const short* __restrict__ p2,
                                               const float* __restrict__ w3,
                                               const float* __restrict__ b3,
                                               float* __restrict__ out) {
  int n = blockIdx.x * 4 + (threadIdx.x >> 6);
  int k = threadIdx.x & 63;
  float v = bf2f(p2[(size_t)n * 64 + k]) * w3[k];
#pragma unroll
  for (int off = 32; off; off >>= 1) v += __shfl_down(v, off, 64);
  if (k == 0) out[n] = 1.0f / (1.0f + __expf(-(v + b3[0])));
}

// ---------------------------------------------------------------------------
extern "C" void kernel_launch(void* const* d_in, const int* in_sizes, int n_in,
                              void* d_out, int out_size, void* d_ws, size_t ws_size,
                              hipStream_t stream) {
  const float* x      = (const float*)d_in[0];
  const int*   ei     = (const int*)d_in[1];
  const int*   batch  = (const int*)d_in[2];
  const float* w_in1  = (const float*)d_in[3];
  const float* b_in1  = (const float*)d_in[4];
  const float* w_in2  = (const float*)d_in[5];
  const float* b_in2  = (const float*)d_in[6];
  const float* gat_w  = (const float*)d_in[7];
  const float* gat_as = (const float*)d_in[8];
  const float* gat_ad = (const float*)d_in[9];
  const float* gat_b  = (const float*)d_in[10];
  const float* gcn_w  = (const float*)d_in[11];
  const float* gcn_b  = (const float*)d_in[12];
  const float* norm_w = (const float*)d_in[13];
  const float* norm_b = (const float*)d_in[14];
  const float* norm_ms= (const float*)d_in[15];
  const float* skip_w = (const float*)d_in[16];
  const float* skip_b = (const float*)d_in[17];
  const float* w_h1   = (const float*)d_in[18];
  const float* b_h1   = (const float*)d_in[19];
  const float* w_h2   = (const float*)d_in[20];
  const float* b_h2   = (const float*)d_in[21];
  const float* w_h3   = (const float*)d_in[22];
  const float* b_h3   = (const float*)d_in[23];
  const float* ewp    = (const float*)d_in[24];
  float* out = (float*)d_out;

  // Workspace (~114 MB). MEGA holds A [N][640] bf16; GB (bf16, stride 640
  // shorts) aliases the first 128 shorts of each A row; EST and head-p2 alias
  // MEGA too.
  char* p = (char*)d_ws;
  const size_t NBH = (size_t)N_NODES * 128 * sizeof(short);  // 12.8 MB
  short* B0   = (short*)p; p += NBH;
  short* B1   = (short*)p; p += NBH;
  short* NRM  = (short*)p; p += NBH;                          // norm output (skip layers)
  short* MEGA = (short*)p; p += (size_t)N_NODES * AROW * sizeof(short);  // 64 MB
  short* GB   = MEGA;
  uint*  EST  = (uint*)MEGA;
  float* SC   = (float*)p; p += (size_t)N_NODES * 16 * sizeof(float);
  int*   CSRC = (int*)p;   p += (size_t)ETOT * sizeof(int);   // dense 6.6 MB
  int*   RBEG = (int*)p;   p += (size_t)N_NODES * sizeof(int);
  int*   REND = (int*)p;   p += (size_t)N_NODES * sizeof(int);
  // zero region: GFILL + 3 GSUM slots
  char*  zbase = p;
  int*   GFILL= (int*)p;   p += (size_t)NBKT * sizeof(int);
  float* GSUM = (float*)p; p += (size_t)3 * NG * 256 * sizeof(float);
  size_t znb  = (size_t)((char*)p - zbase);
  int*   BKTB = (int*)p;   p += (size_t)NBKT * sizeof(int);
  int*   GCNT = (int*)p;   p += (size_t)NG * sizeof(int);
  float* DINV = (float*)p; p += (size_t)N_NODES * sizeof(float);
  short* WT0  = (short*)p; p += 16384 * sizeof(short);
  short* WT1  = (short*)p; p += 16384 * sizeof(short);
  short* WTL2 = (short*)p; p += 3 * 32768 * sizeof(short);   // [gat;gcn] K=256
  short* WTS  = (short*)p; p += 2 * 16384 * sizeof(short);
  short* WTH1 = (short*)p; p += 16384 * sizeof(short);
  short* WTH2 = (short*)p; p += 8192 * sizeof(short);
  short* ATTW = (short*)p; p += 3 * 2048 * sizeof(short);    // [l][16][128]
  float* BSUM = (float*)p; p += 3 * 128 * sizeof(float);

  const int GB_ = (N_NODES + 63) / 64;    // 782 gemm blocks

  // --- CSR build + conversions/prep ---
  hipMemsetAsync(zbase, 0, znb, stream);
  bucket_k<<<NBK1, 256, 0, stream>>>(ei, GFILL, EST);
  bktscan_k<<<1, 256, 0, stream>>>(GFILL, BKTB);
  group_k<<<196, 256, 0, stream>>>(GFILL, BKTB, EST, ewp, CSRC, RBEG, REND, DINV);
  gcnt_k<<<1, 128, 0, stream>>>(batch, GCNT);
  convx_k<<<(N_NODES * 128) / 1024, 256, 0, stream>>>(x, B0);
  prep_k<<<48, 256, 0, stream>>>(w_in1, w_in2, gat_w, gcn_w, skip_w, w_h1, w_h2,
                                 WT0, WT1, WTL2, WTS, WTH1, WTH2);
  attprep_k<<<1, 256, 0, stream>>>(gat_w, gat_as, gat_ad, gat_b, gcn_b, ATTW, BSUM);

  // --- input MLP: B0 -> B1 -> B0 (h0) ---
  bgemm_k<128, 1, 0, 0><<<GB_, 256, 0, stream>>>(B0, WT0, b_in1, nullptr, B1, nullptr, N_NODES);
  bgemm_k<128, 0, 0, 0><<<GB_, 256, 0, stream>>>(B1, WT1, b_in2, nullptr, B0, nullptr, N_NODES);

  short* h = B0;
  for (int i = 0; i < 3; ++i) {
    short* hn = (h == B0) ? B1 : B0;
    float* gsum_i = GSUM + (size_t)i * NG * 256;
    // scores: SC[N,16] = h @ ATTW^T (cols 0-3 src, 4-7 dst per head)
    bgemm_k<16, 0, 0, 1><<<GB_, 256, 0, stream>>>(h, ATTW + (size_t)i * 2048,
                                                  nullptr, nullptr, nullptr, SC, N_NODES);
    agg_k<<<N_NODES / 4, 256, 0, stream>>>(h, SC, RBEG, REND, CSRC, DINV, ewp, MEGA);
    aggproj_k<<<GB_, 256, 0, stream>>>(MEGA, WTL2 + (size_t)i * 32768,
                                       BSUM + i * 128, GB, N_NODES);
    stats_k<<<N_NODES / 16, 256, 0, stream>>>(GB, batch, gsum_i);
    if (i == 1) {
      normelu_k<<<N_NODES / 4, 256, 0, stream>>>(GB, batch, gsum_i, GCNT,
          norm_w + (size_t)i * 128, norm_b + (size_t)i * 128, norm_ms + (size_t)i * 128,
          hn);
    } else {
      normelu_k<<<N_NODES / 4, 256, 0, stream>>>(GB, batch, gsum_i, GCNT,
          norm_w + (size_t)i * 128, norm_b + (size_t)i * 128, norm_ms + (size_t)i * 128,
          NRM);
      const short* wts = WTS + (size_t)(i == 0 ? 0 : 1) * 16384;
      bgemm_k<128, 0, 1, 0><<<GB_, 256, 0, stream>>>(h, wts, skip_b + (size_t)i * 128,
                                                     NRM, hn, nullptr, N_NODES);
    }
    h = hn;
  }

  // --- head ---  (h = B1; B0 and MEGA free)
  bgemm_k<128, 1, 0, 0><<<GB_, 256, 0, stream>>>(h, WTH1, b_h1, nullptr, B0, nullptr, N_NODES);
  bgemm_k<64, 1, 0, 0><<<GB_, 256, 0, stream>>>(B0, WTH2, b_h2, nullptr, MEGA, nullptr, N_NODES);
  head3_k<<<N_NODES / 4, 256, 0, stream>>>(MEGA, w_h3, b_h3, out);
}

// Round 10
// 856.002 us; speedup vs baseline: 1.0267x; 1.0267x over previous
//
#include <hip/hip_runtime.h>
#include <hip/hip_fp16.h>

typedef unsigned int uint;
typedef unsigned short ushort;
typedef __attribute__((ext_vector_type(8))) short short8;   // 8 bf16 in 4 VGPRs
typedef __attribute__((ext_vector_type(4))) float f32x4;
typedef __attribute__((ext_vector_type(2))) float f32x2;    // v_pk_fma_f32

#define N_NODES 50000
#define N_EDGES 800000
#define ETOT    (2 * N_EDGES + N_NODES)   // 1,650,000
#define NG      64
#define NBKT    256                       // coarse buckets (dst>>8), 196 used
#define MAXB    10240                     // EST staging capacity per bucket
#define EPB     8192                      // edges per bucket_k block
#define NBK1    ((ETOT + EPB - 1) / EPB)  // 202
#define AROW    640                       // MEGA row stride in shorts (1280 B)

__device__ __forceinline__ short f2bf(float f) {   // RNE float->bf16
  uint u = __float_as_uint(f);
  u += 0x7fffu + ((u >> 16) & 1u);
  return (short)(u >> 16);
}
__device__ __forceinline__ float bf2f(short s) {
  return __uint_as_float(((uint)(ushort)s) << 16);
}
__device__ __forceinline__ uint packbf(float a, float b) {
  return (uint)(ushort)f2bf(a) | ((uint)(ushort)f2bf(b) << 16);
}
__device__ __forceinline__ uint pkh2(float a, float b) {   // 2xfp16 pack
  __half2 h = __floats2half2_rn(a, b);
  return *(uint*)&h;
}
__device__ __forceinline__ float2 uph2(uint u) {           // 2xfp16 unpack
  __half2 h = *(__half2*)&u;
  return __half22float2(h);
}

// ---------------------------------------------------------------------------
// K1: bucket edges by dst>>8 into padded staging. LDS histogram; one global
// atomic per (block,bin). Entry: src(16b) | dst_low(8b)<<16 | selfloop<<24
// ---------------------------------------------------------------------------
__global__ __launch_bounds__(256) void bucket_k(const int* __restrict__ ei,
                                                int* __restrict__ gfill,
                                                uint* __restrict__ est) {
  __shared__ int hist[NBKT];
  __shared__ int cursor[NBKT];
  const int tid = threadIdx.x;
  hist[tid] = 0;
  __syncthreads();
  const int e0 = blockIdx.x * EPB;
#pragma unroll 4
  for (int i = 0; i < EPB / 256; ++i) {
    int e = e0 + i * 256 + tid;
    if (e < ETOT) {
      int d;
      if (e < N_EDGES)          d = ei[N_EDGES + e];
      else if (e < 2 * N_EDGES) d = ei[e - N_EDGES];
      else                      d = e - 2 * N_EDGES;
      atomicAdd(&hist[d >> 8], 1);
    }
  }
  __syncthreads();
  cursor[tid] = atomicAdd(&gfill[tid], hist[tid]);
  __syncthreads();
#pragma unroll 4
  for (int i = 0; i < EPB / 256; ++i) {
    int e = e0 + i * 256 + tid;
    if (e < ETOT) {
      int s, d, fl = 0;
      if (e < N_EDGES)          { s = ei[e];           d = ei[N_EDGES + e]; }
      else if (e < 2 * N_EDGES) { s = ei[e];           d = ei[e - N_EDGES]; }
      else                      { s = e - 2 * N_EDGES; d = s; fl = 1; }
      int b = d >> 8;
      int slot = atomicAdd(&cursor[b], 1);
      est[(size_t)b * MAXB + slot] = (uint)s | ((uint)(d & 255) << 16) | ((uint)fl << 24);
    }
  }
}

// ---------------------------------------------------------------------------
// K2: per-bucket regroup by dst low byte -> DENSE CSR + dinv.
// Computes its own dense base (prefix of gfill[0..b)) in-block.
// ---------------------------------------------------------------------------
__global__ __launch_bounds__(256) void group_k(const int* __restrict__ gfill,
                                               const uint* __restrict__ est,
                                               const float* __restrict__ ewp,
                                               int* __restrict__ csrc,
                                               int* __restrict__ rbeg,
                                               int* __restrict__ rend,
                                               float* __restrict__ dinv) {
  __shared__ int hist[NBKT];
  __shared__ int cursor[NBKT];
  __shared__ int wsum[4];
  __shared__ int bsum[4];
  const int b = blockIdx.x;
  const int tid = threadIdx.x;
  const int lane = tid & 63, wid = tid >> 6;
  const int cnt = gfill[b];
  // dense base = sum(gfill[0..b))
  {
    int vv = (tid < b) ? gfill[tid] : 0;
#pragma unroll
    for (int off = 32; off; off >>= 1) vv += __shfl_xor(vv, off, 64);
    if (lane == 0) bsum[wid] = vv;
  }
  hist[tid] = 0;
  __syncthreads();
  const int gb = bsum[0] + bsum[1] + bsum[2] + bsum[3];
  const uint* basep = est + (size_t)b * MAXB;
  for (int i = tid; i < cnt; i += 256)
    atomicAdd(&hist[(basep[i] >> 16) & 255], 1);
  __syncthreads();
  int v = hist[tid];
  int x = v;
#pragma unroll
  for (int d = 1; d < 64; d <<= 1) {
    int t = __shfl_up(x, d, 64);
    if (lane >= d) x += t;
  }
  if (lane == 63) wsum[wid] = x;
  __syncthreads();
  int woff = 0;
#pragma unroll
  for (int j = 0; j < 4; ++j) if (j < wid) woff += wsum[j];
  int excl = woff + x - v;
  cursor[tid] = excl;
  int node = b * 256 + tid;
  if (node < N_NODES) {
    rbeg[node] = gb + excl;
    rend[node] = gb + excl + v;
    float deg = ewp[0] * (float)(v - 1) + 2.0f;
    dinv[node] = (deg > 0.f) ? rsqrtf(deg) : 0.f;
  }
  __syncthreads();
  for (int i = tid; i < cnt; i += 256) {
    uint en = basep[i];
    int dlow = (en >> 16) & 255;
    int slot = atomicAdd(&cursor[dlow], 1);
    csrc[gb + slot] = (int)(en & 0xffffu) | (int)((en >> 24) << 31);
  }
}

// Graph sizes via binary search on sorted batch
__global__ __launch_bounds__(128) void gcnt_k(const int* __restrict__ batch,
                                              int* __restrict__ gcnt) {
  __shared__ int lb[NG + 1];
  int g = threadIdx.x;
  if (g <= NG) {
    int lo = 0, hi = N_NODES;
    while (lo < hi) {
      int mid = (lo + hi) >> 1;
      if (batch[mid] < g) lo = mid + 1; else hi = mid;
    }
    lb[g] = lo;
  }
  __syncthreads();
  if (g < NG) gcnt[g] = lb[g + 1] - lb[g];
}

// ---------------------------------------------------------------------------
// Weight prep. All source mats are [128(k) x ncol] fp32.
// ---------------------------------------------------------------------------
__global__ __launch_bounds__(256) void prep_k(const float* __restrict__ w_in1,
                                              const float* __restrict__ w_in2,
                                              const float* __restrict__ gat_w,
                                              const float* __restrict__ gcn_w,
                                              const float* __restrict__ skip_w,
                                              const float* __restrict__ w_h1,
                                              const float* __restrict__ w_h2,
                                              short* __restrict__ WT0,
                                              short* __restrict__ WT1,
                                              short* __restrict__ WTL2,
                                              short* __restrict__ WTS,
                                              short* __restrict__ WTH1,
                                              short* __restrict__ WTH2) {
  int mat = blockIdx.x >> 2, qr = blockIdx.x & 3;
  const float* src; short* dst; int ncol = 128, dstride = 128, doff = 0;
  switch (mat) {
    case 0:  src = w_in1; dst = WT0; break;
    case 1:  src = w_in2; dst = WT1; break;
    case 2: case 3: case 4:
      src = gat_w + (size_t)(mat - 2) * 16384; dst = WTL2 + (size_t)(mat - 2) * 32768;
      dstride = 256; break;
    case 5: case 6: case 7:
      src = gcn_w + (size_t)(mat - 5) * 16384; dst = WTL2 + (size_t)(mat - 5) * 32768;
      dstride = 256; doff = 128; break;
    case 8:  src = skip_w;             dst = WTS;         break;
    case 9:  src = skip_w + 2 * 16384; dst = WTS + 16384; break;
    case 10: src = w_h1; dst = WTH1; break;
    default: src = w_h2; dst = WTH2; ncol = 64; break;
  }
  int total = 128 * ncol, chunk = total / 4;
  for (int d = qr * chunk + threadIdx.x; d < (qr + 1) * chunk; d += 256) {
    int col = d >> 7, k = d & 127;
    dst[col * dstride + doff + k] = f2bf(src[k * ncol + col]);
  }
}

// ---------------------------------------------------------------------------
// Attention projection + bias sums (ATTW rows 8..15 zero)
// ---------------------------------------------------------------------------
__global__ __launch_bounds__(256) void attprep_k(const float* __restrict__ gat_w,
                                                 const float* __restrict__ asrc,
                                                 const float* __restrict__ adst,
                                                 const float* __restrict__ gat_b,
                                                 const float* __restrict__ gcn_b,
                                                 short* __restrict__ ATTW,
                                                 float* __restrict__ BSUM) {
  const int tid = threadIdx.x;
  for (int t = tid; t < 3072; t += 256) {          // 3 layers x 8 rows x 128 k
    int l = t >> 10, rem = t & 1023;
    int r = rem >> 7, k = rem & 127;
    int hd = r & 3;
    const float* av = (r < 4) ? (asrc + l * 128 + hd * 32) : (adst + l * 128 + hd * 32);
    const float* wrow = gat_w + (size_t)l * 16384 + k * 128 + hd * 32;
    float s = 0.f;
#pragma unroll
    for (int c = 0; c < 32; ++c) s = fmaf(wrow[c], av[c], s);
    ATTW[(size_t)l * 2048 + r * 128 + k] = f2bf(s);
  }
  for (int t = tid; t < 3072; t += 256)            // zero rows 8..15
    ATTW[(size_t)(t >> 10) * 2048 + 1024 + (t & 1023)] = 0;
  for (int t = tid; t < 384; t += 256) {
    int l = t >> 7, c = t & 127;
    BSUM[t] = gat_b[l * 128 + c] + gcn_b[l * 128 + c];
  }
}

// ---------------------------------------------------------------------------
// bf16 MFMA GEMM (K=128).
// AF32: A read from fp32 (Af) and packed to bf16 fragments in-register.
// NORM: epilogue adds graphnorm+ELU of GB[row*AROW+col] (fused normelu+skip).
// F32OUT -> outf (row stride NCOL).
// ---------------------------------------------------------------------------
template <int NCOL, int RELU, int F32OUT, int AF32, int NORM>
__global__ __launch_bounds__(256) void bgemm_k(const short* __restrict__ A,
                                               const float* __restrict__ Af,
                                               const short* __restrict__ WT,
                                               const float* __restrict__ bias,
                                               const short* __restrict__ gb_,
                                               const int* __restrict__ batch,
                                               const int* __restrict__ gcnt,
                                               const float* __restrict__ gsum,
                                               const float* __restrict__ nw,
                                               const float* __restrict__ nb_,
                                               const float* __restrict__ nms,
                                               short* __restrict__ outb,
                                               float* __restrict__ outf, int M) {
  constexpr int NT = NCOL / 16;
  const int lane = threadIdx.x & 63;
  const int wid = threadIdx.x >> 6;
  const int mbase = blockIdx.x * 64 + wid * 16;
  const int l15 = lane & 15, q = lane >> 4;
  int arow = mbase + l15; if (arow > M - 1) arow = M - 1;
  const short* bp = WT + (size_t)l15 * 128 + q * 8;
  f32x4 acc[NT];
#pragma unroll
  for (int t = 0; t < NT; ++t) acc[t] = (f32x4)0.f;
#pragma unroll
  for (int c = 0; c < 4; ++c) {
    short8 av;
    if (AF32) {
      const float* apf = Af + (size_t)arow * 128 + q * 8 + c * 32;
      float4 fa = *(const float4*)apf;
      float4 fb = *(const float4*)(apf + 4);
      uint2 lo = make_uint2(packbf(fa.x, fa.y), packbf(fa.z, fa.w));
      uint2 hi = make_uint2(packbf(fb.x, fb.y), packbf(fb.z, fb.w));
      uint4 all = make_uint4(lo.x, lo.y, hi.x, hi.y);
      av = *(short8*)&all;
    } else {
      av = *(const short8*)(A + (size_t)arow * 128 + q * 8 + c * 32);
    }
#pragma unroll
    for (int t = 0; t < NT; ++t) {
      short8 bv = *(const short8*)(bp + (size_t)t * 16 * 128 + c * 32);
      acc[t] = __builtin_amdgcn_mfma_f32_16x16x32_bf16(av, bv, acc[t], 0, 0, 0);
    }
  }
#pragma unroll
  for (int t = 0; t < NT; ++t) {
    int col = t * 16 + l15;
    float bb = bias ? bias[col] : 0.f;
#pragma unroll
    for (int r = 0; r < 4; ++r) {
      int row = mbase + q * 4 + r;
      if (row < M) {
        float v = acc[t][r] + bb;
        if (NORM) {
          int b = batch[row];
          float cinv = 1.0f / fmaxf((float)gcnt[b], 1.0f);
          float mean = gsum[b * 256 + col] * cinv;
          float msq  = gsum[b * 256 + 128 + col] * cinv;
          float ms = nms[col];
          float var = fmaxf(msq - (2.0f * ms - ms * ms) * mean * mean, 0.f);
          float g = bf2f(gb_[(size_t)row * AROW + col]);
          float tn = (g - mean * ms) * rsqrtf(var + 1e-5f) * nw[col] + nb_[col];
          tn = (tn > 0.f) ? tn : (__expf(tn) - 1.0f);
          v += tn;
        }
        if (RELU) v = v > 0.f ? v : 0.f;
        if (F32OUT) outf[(size_t)row * NCOL + col] = v;
        else        outb[(size_t)row * NCOL + col] = f2bf(v);
      }
    }
  }
}

// ---------------------------------------------------------------------------
// Fused coef + GAT/GCN aggregation, PER-HEAD. One node per wave.
// phase1: one edge per lane -> exps/c2/src into LDS uint4 (wave-sync)
// phase2: 2 edges/iter, 32 lanes each, 4 feats/lane; ds_read_b128 per edge.
// ---------------------------------------------------------------------------
__global__ __launch_bounds__(256) void agg_k(const short* __restrict__ h,
                                             const float* __restrict__ sc,
                                             const int* __restrict__ rbeg,
                                             const int* __restrict__ rend,
                                             const int* __restrict__ cs,
                                             const float* __restrict__ dinv,
                                             const float* __restrict__ ewp,
                                             short* __restrict__ A) {
  __shared__ uint4 lco[4][64];       // [wave][edge-in-chunk] {p01,p23,c2|src,0}
  const int n = blockIdx.x * 4 + (threadIdx.x >> 6);
  const int wv = threadIdx.x >> 6;
  const int l = threadIdx.x & 63;
  const int sub = l >> 5;            // which edge of the pair (phase2)
  const int f4 = l & 31;             // feature quad (phase2)
  const float ew0 = ewp[0];
  const float dn = dinv[n];
  const f32x4 sdv = *(const f32x4*)(sc + n * 16 + 4);
  const int beg = rbeg[n], end = rend[n];
  float den[4] = {0.f, 0.f, 0.f, 0.f};
  f32x2 ag[4][2], ac[2];
#pragma unroll
  for (int hd = 0; hd < 4; ++hd) { ag[hd][0] = (f32x2)0.f; ag[hd][1] = (f32x2)0.f; }
  ac[0] = (f32x2)0.f; ac[1] = (f32x2)0.f;

  for (int c0 = beg; c0 < end; c0 += 64) {
    const int nc = min(64, end - c0);
    // ---- phase 1: this lane's edge -> LDS ----
    {
      uint4 w = make_uint4(0u, 0u, 0u, 0u);
      int e = c0 + l;
      if (e < end) {
        int raw = cs[e];
        int s = raw & 0x7fffffff;
        float wt = (raw < 0) ? 2.0f : ew0;
        f32x4 ssv = *(const f32x4*)(sc + (size_t)s * 16);
        float a0 = ssv[0] + sdv[0]; a0 = fmaxf(a0, 0.2f * a0);
        float a1 = ssv[1] + sdv[1]; a1 = fmaxf(a1, 0.2f * a1);
        float a2 = ssv[2] + sdv[2]; a2 = fmaxf(a2, 0.2f * a2);
        float a3 = ssv[3] + sdv[3]; a3 = fmaxf(a3, 0.2f * a3);
        float e0 = __expf(a0), e1 = __expf(a1);
        float e2 = __expf(a2), e3 = __expf(a3);
        den[0] += e0; den[1] += e1; den[2] += e2; den[3] += e3;
        float c2 = dinv[s] * wt * dn;
        __half hc = __float2half(c2);
        w = make_uint4(pkh2(e0, e1), pkh2(e2, e3),
                       (uint)(*(ushort*)&hc) | ((uint)s << 16), 0u);
      }
      lco[wv][l] = w;
    }
    // same wave wrote, same wave reads: no __syncthreads needed
    const int pairs = (nc + 1) & ~1;
#pragma unroll 2
    for (int j = sub; j < pairs; j += 2) {
      uint4 cw = lco[wv][j];
      int s = (int)(cw.z >> 16);
      float2 p01 = uph2(cw.x);
      float2 p23 = uph2(cw.y);
      ushort hc = (ushort)(cw.z & 0xffffu);
      float c2 = __half2float(*(__half*)&hc);
      uint2 u = *(const uint2*)(h + (size_t)s * 128 + f4 * 4);
      f32x2 va, vb;
      va.x = __uint_as_float(u.x << 16);
      va.y = __uint_as_float(u.x & 0xffff0000u);
      vb.x = __uint_as_float(u.y << 16);
      vb.y = __uint_as_float(u.y & 0xffff0000u);
      f32x2 cc;
      cc.x = p01.x; cc.y = p01.x;
      ag[0][0] += cc * va; ag[0][1] += cc * vb;
      cc.x = p01.y; cc.y = p01.y;
      ag[1][0] += cc * va; ag[1][1] += cc * vb;
      cc.x = p23.x; cc.y = p23.x;
      ag[2][0] += cc * va; ag[2][1] += cc * vb;
      cc.x = p23.y; cc.y = p23.y;
      ag[3][0] += cc * va; ag[3][1] += cc * vb;
      cc.x = c2; cc.y = c2;
      ac[0] += cc * va; ac[1] += cc * vb;
    }
  }

#pragma unroll
  for (int off = 1; off < 64; off <<= 1) {
    den[0] += __shfl_xor(den[0], off, 64);
    den[1] += __shfl_xor(den[1], off, 64);
    den[2] += __shfl_xor(den[2], off, 64);
    den[3] += __shfl_xor(den[3], off, 64);
  }
#pragma unroll
  for (int hd = 0; hd < 4; ++hd)
#pragma unroll
    for (int i = 0; i < 2; ++i) {
      f32x2 t = ag[hd][i];
      t.x += __shfl_xor(t.x, 32, 64);
      t.y += __shfl_xor(t.y, 32, 64);
      ag[hd][i] = t;
    }
#pragma unroll
  for (int i = 0; i < 2; ++i) {
    f32x2 t = ac[i];
    t.x += __shfl_xor(t.x, 32, 64);
    t.y += __shfl_xor(t.y, 32, 64);
    ac[i] = t;
  }

  float inv[4] = {1.0f / (den[0] + 1e-16f), 1.0f / (den[1] + 1e-16f),
                  1.0f / (den[2] + 1e-16f), 1.0f / (den[3] + 1e-16f)};
  short* base = A + (size_t)n * AROW;
  if (sub == 0) {
#pragma unroll
    for (int hd = 0; hd < 2; ++hd) {
      float iv = inv[hd];
      *(uint2*)(base + hd * 128 + f4 * 4) =
          make_uint2(packbf(ag[hd][0].x * iv, ag[hd][0].y * iv),
                     packbf(ag[hd][1].x * iv, ag[hd][1].y * iv));
    }
    *(uint2*)(base + 512 + f4 * 4) =
        make_uint2(packbf(ac[0].x, ac[0].y), packbf(ac[1].x, ac[1].y));
  } else {
#pragma unroll
    for (int hd = 2; hd < 4; ++hd) {
      float iv = inv[hd];
      *(uint2*)(base + hd * 128 + f4 * 4) =
          make_uint2(packbf(ag[hd][0].x * iv, ag[hd][0].y * iv),
                     packbf(ag[hd][1].x * iv, ag[hd][1].y * iv));
    }
  }
}

// ---------------------------------------------------------------------------
// Head-structured projection; output GB bf16 aliases first 128 shorts of each
// MEGA row (stride AROW). No __restrict__ on A/GB keeps program order.
// ---------------------------------------------------------------------------
__global__ __launch_bounds__(256) void aggproj_k(const short* A,
                                                 const short* __restrict__ WT,
                                                 const float* __restrict__ bsum,
                                                 short* GB, int M) {
  const int lane = threadIdx.x & 63;
  const int wid = threadIdx.x >> 6;
  const int mbase = blockIdx.x * 64 + wid * 16;
  const int l15 = lane & 15, q = lane >> 4;
  int arow = mbase + l15; if (arow > M - 1) arow = M - 1;
  const short* ap = A + (size_t)arow * AROW + q * 8;
  const short* bp = WT + (size_t)l15 * 256 + q * 8;
  f32x4 acc[8];
#pragma unroll
  for (int t = 0; t < 8; ++t) acc[t] = (f32x4)0.f;
  short8 avg[4];
#pragma unroll
  for (int c = 0; c < 4; ++c) avg[c] = *(const short8*)(ap + 512 + c * 32);
#pragma unroll
  for (int hd = 0; hd < 4; ++hd) {
    short8 avh[4];
#pragma unroll
    for (int c = 0; c < 4; ++c) avh[c] = *(const short8*)(ap + hd * 128 + c * 32);
#pragma unroll
    for (int tt = 0; tt < 2; ++tt) {
      int t = hd * 2 + tt;
      const short* bpt = bp + (size_t)t * 16 * 256;
#pragma unroll
      for (int c = 0; c < 4; ++c) {
        short8 bv = *(const short8*)(bpt + c * 32);
        acc[t] = __builtin_amdgcn_mfma_f32_16x16x32_bf16(avh[c], bv, acc[t], 0, 0, 0);
      }
#pragma unroll
      for (int c = 0; c < 4; ++c) {
        short8 bv = *(const short8*)(bpt + 128 + c * 32);
        acc[t] = __builtin_amdgcn_mfma_f32_16x16x32_bf16(avg[c], bv, acc[t], 0, 0, 0);
      }
    }
  }
#pragma unroll
  for (int t = 0; t < 8; ++t) {
    int col = t * 16 + l15;
    float bb = bsum[col];
#pragma unroll
    for (int r = 0; r < 4; ++r) {
      int row = mbase + q * 4 + r;
      if (row < M) GB[(size_t)row * AROW + col] = f2bf(acc[t][r] + bb);
    }
  }
}

// ---------------------------------------------------------------------------
// GraphNorm stats on GB (bf16, row stride AROW). Thread = feature pair.
// ---------------------------------------------------------------------------
__global__ __launch_bounds__(256) void stats_k(const short* __restrict__ gb,
                                               const int* __restrict__ batch,
                                               float* __restrict__ gsum) {
  int c2 = threadIdx.x & 63;          // feature pair: 2c2, 2c2+1
  int qr = threadIdx.x >> 6;          // row group
  int nb = blockIdx.x * 16;
  float s0 = 0.f, s1 = 0.f, q0 = 0.f, q1 = 0.f;
  int curb = -1;
  for (int i = qr; i < 16; i += 4) {
    int n = nb + i;
    int b = batch[n];
    if (b != curb) {
      if (curb >= 0) {
        atomicAdd(&gsum[curb * 256 + 2 * c2], s0);
        atomicAdd(&gsum[curb * 256 + 2 * c2 + 1], s1);
        atomicAdd(&gsum[curb * 256 + 128 + 2 * c2], q0);
        atomicAdd(&gsum[curb * 256 + 128 + 2 * c2 + 1], q1);
      }
      curb = b; s0 = s1 = q0 = q1 = 0.f;
    }
    uint u = *(const uint*)(gb + (size_t)n * AROW + 2 * c2);
    float v0 = __uint_as_float(u << 16);
    float v1 = __uint_as_float(u & 0xffff0000u);
    s0 += v0; q0 = fmaf(v0, v0, q0);
    s1 += v1; q1 = fmaf(v1, v1, q1);
  }
  if (curb >= 0) {
    atomicAdd(&gsum[curb * 256 + 2 * c2], s0);
    atomicAdd(&gsum[curb * 256 + 2 * c2 + 1], s1);
    atomicAdd(&gsum[curb * 256 + 128 + 2 * c2], q0);
    atomicAdd(&gsum[curb * 256 + 128 + 2 * c2 + 1], q1);
  }
}

// GraphNorm + ELU: GB bf16 (stride AROW) -> outb bf16 (stride 128). Layer 1 only.
__global__ __launch_bounds__(256) void normelu_k(const short* __restrict__ gb,
                                                 const int* __restrict__ batch,
                                                 const float* __restrict__ gsum,
                                                 const int* __restrict__ gcnt,
                                                 const float* __restrict__ nw,
                                                 const float* __restrict__ nb_,
                                                 const float* __restrict__ nms,
                                                 short* __restrict__ outb) {
  int n = blockIdx.x * 4 + (threadIdx.x >> 6);
  int c2 = threadIdx.x & 63;
  int b = batch[n];
  float cntf = fmaxf((float)gcnt[b], 1.0f);
  float cinv = 1.0f / cntf;
  uint u = *(const uint*)(gb + (size_t)n * AROW + 2 * c2);
  float o[2];
#pragma unroll
  for (int k = 0; k < 2; ++k) {
    int c = 2 * c2 + k;
    float mean = gsum[b * 256 + c] * cinv;
    float msq  = gsum[b * 256 + 128 + c] * cinv;
    float ms = nms[c];
    float var = fmaxf(msq - (2.0f * ms - ms * ms) * mean * mean, 0.f);
    float v = (k == 0) ? __uint_as_float(u << 16) : __uint_as_float(u & 0xffff0000u);
    float t = (v - mean * ms) * rsqrtf(var + 1e-5f) * nw[c] + nb_[c];
    o[k] = (t > 0.f) ? t : (__expf(t) - 1.0f);
  }
  *(uint*)(outb + (size_t)n * 128 + 2 * c2) = packbf(o[0], o[1]);
}

// Final head: sigmoid(<p2[n,:64], w3> + b3), p2 bf16
__global__ __launch_bounds__(256) void head3_k(const short* __restrict__ p2,
                                               const float* __restrict__ w3,
                                               const float* __restrict__ b3,
                                               float* __restrict__ out) {
  int n = blockIdx.x * 4 + (threadIdx.x >> 6);
  int k = threadIdx.x & 63;
  float v = bf2f(p2[(size_t)n * 64 + k]) * w3[k];
#pragma unroll
  for (int off = 32; off; off >>= 1) v += __shfl_down(v, off, 64);
  if (k == 0) out[n] = 1.0f / (1.0f + __expf(-(v + b3[0])));
}

// ---------------------------------------------------------------------------
extern "C" void kernel_launch(void* const* d_in, const int* in_sizes, int n_in,
                              void* d_out, int out_size, void* d_ws, size_t ws_size,
                              hipStream_t stream) {
  const float* x      = (const float*)d_in[0];
  const int*   ei     = (const int*)d_in[1];
  const int*   batch  = (const int*)d_in[2];
  const float* w_in1  = (const float*)d_in[3];
  const float* b_in1  = (const float*)d_in[4];
  const float* w_in2  = (const float*)d_in[5];
  const float* b_in2  = (const float*)d_in[6];
  const float* gat_w  = (const float*)d_in[7];
  const float* gat_as = (const float*)d_in[8];
  const float* gat_ad = (const float*)d_in[9];
  const float* gat_b  = (const float*)d_in[10];
  const float* gcn_w  = (const float*)d_in[11];
  const float* gcn_b  = (const float*)d_in[12];
  const float* norm_w = (const float*)d_in[13];
  const float* norm_b = (const float*)d_in[14];
  const float* norm_ms= (const float*)d_in[15];
  const float* skip_w = (const float*)d_in[16];
  const float* skip_b = (const float*)d_in[17];
  const float* w_h1   = (const float*)d_in[18];
  const float* b_h1   = (const float*)d_in[19];
  const float* w_h2   = (const float*)d_in[20];
  const float* b_h2   = (const float*)d_in[21];
  const float* w_h3   = (const float*)d_in[22];
  const float* b_h3   = (const float*)d_in[23];
  const float* ewp    = (const float*)d_in[24];
  float* out = (float*)d_out;

  // Workspace (~101 MB). MEGA holds A [N][640] bf16; GB aliases the first 128
  // shorts of each A row; EST staging and head-p2 alias MEGA too.
  char* p = (char*)d_ws;
  const size_t NBH = (size_t)N_NODES * 128 * sizeof(short);  // 12.8 MB
  short* B0   = (short*)p; p += NBH;
  short* B1   = (short*)p; p += NBH;
  short* MEGA = (short*)p; p += (size_t)N_NODES * AROW * sizeof(short);  // 64 MB
  short* GB   = MEGA;
  uint*  EST  = (uint*)MEGA;
  float* SC   = (float*)p; p += (size_t)N_NODES * 16 * sizeof(float);
  int*   CSRC = (int*)p;   p += (size_t)ETOT * sizeof(int);   // dense 6.6 MB
  int*   RBEG = (int*)p;   p += (size_t)N_NODES * sizeof(int);
  int*   REND = (int*)p;   p += (size_t)N_NODES * sizeof(int);
  // zero region: GFILL + 3 GSUM slots
  char*  zbase = p;
  int*   GFILL= (int*)p;   p += (size_t)NBKT * sizeof(int);
  float* GSUM = (float*)p; p += (size_t)3 * NG * 256 * sizeof(float);
  size_t znb  = (size_t)((char*)p - zbase);
  int*   GCNT = (int*)p;   p += (size_t)NG * sizeof(int);
  float* DINV = (float*)p; p += (size_t)N_NODES * sizeof(float);
  short* WT0  = (short*)p; p += 16384 * sizeof(short);
  short* WT1  = (short*)p; p += 16384 * sizeof(short);
  short* WTL2 = (short*)p; p += 3 * 32768 * sizeof(short);   // [gat;gcn] K=256
  short* WTS  = (short*)p; p += 2 * 16384 * sizeof(short);
  short* WTH1 = (short*)p; p += 16384 * sizeof(short);
  short* WTH2 = (short*)p; p += 8192 * sizeof(short);
  short* ATTW = (short*)p; p += 3 * 2048 * sizeof(short);    // [l][16][128]
  float* BSUM = (float*)p; p += 3 * 128 * sizeof(float);

  const int GB_ = (N_NODES + 63) / 64;    // 782 gemm blocks
  const short* nullb = nullptr;

  // --- CSR build + prep ---
  hipMemsetAsync(zbase, 0, znb, stream);
  bucket_k<<<NBK1, 256, 0, stream>>>(ei, GFILL, EST);
  group_k<<<196, 256, 0, stream>>>(GFILL, EST, ewp, CSRC, RBEG, REND, DINV);
  gcnt_k<<<1, 128, 0, stream>>>(batch, GCNT);
  prep_k<<<48, 256, 0, stream>>>(w_in1, w_in2, gat_w, gcn_w, skip_w, w_h1, w_h2,
                                 WT0, WT1, WTL2, WTS, WTH1, WTH2);
  attprep_k<<<1, 256, 0, stream>>>(gat_w, gat_as, gat_ad, gat_b, gcn_b, ATTW, BSUM);

  // --- input MLP: x(fp32) -> B1 -> B0 (h0) ---
  bgemm_k<128, 1, 0, 1, 0><<<GB_, 256, 0, stream>>>(nullb, x, WT0, b_in1,
      nullb, nullptr, nullptr, nullptr, nullptr, nullptr, nullptr, B1, nullptr, N_NODES);
  bgemm_k<128, 0, 0, 0, 0><<<GB_, 256, 0, stream>>>(B1, nullptr, WT1, b_in2,
      nullb, nullptr, nullptr, nullptr, nullptr, nullptr, nullptr, B0, nullptr, N_NODES);

  short* h = B0;
  for (int i = 0; i < 3; ++i) {
    short* hn = (h == B0) ? B1 : B0;
    float* gsum_i = GSUM + (size_t)i * NG * 256;
    const float* nw  = norm_w  + (size_t)i * 128;
    const float* nb  = norm_b  + (size_t)i * 128;
    const float* nms = norm_ms + (size_t)i * 128;
    // scores: SC[N,16] = h @ ATTW^T (cols 0-3 src, 4-7 dst per head)
    bgemm_k<16, 0, 1, 0, 0><<<GB_, 256, 0, stream>>>(h, nullptr,
        ATTW + (size_t)i * 2048, nullptr, nullb, nullptr, nullptr, nullptr,
        nullptr, nullptr, nullptr, nullptr, SC, N_NODES);
    agg_k<<<N_NODES / 4, 256, 0, stream>>>(h, SC, RBEG, REND, CSRC, DINV, ewp, MEGA);
    aggproj_k<<<GB_, 256, 0, stream>>>(MEGA, WTL2 + (size_t)i * 32768,
                                       BSUM + i * 128, GB, N_NODES);
    stats_k<<<N_NODES / 16, 256, 0, stream>>>(GB, batch, gsum_i);
    if (i == 1) {
      normelu_k<<<N_NODES / 4, 256, 0, stream>>>(GB, batch, gsum_i, GCNT,
                                                 nw, nb, nms, hn);
    } else {
      // hn = normelu(GB) + h @ skip_w + skip_b   (fused epilogue)
      const short* wts = WTS + (size_t)(i == 0 ? 0 : 1) * 16384;
      bgemm_k<128, 0, 0, 0, 1><<<GB_, 256, 0, stream>>>(h, nullptr, wts,
          skip_b + (size_t)i * 128, GB, batch, GCNT, gsum_i, nw, nb, nms,
          hn, nullptr, N_NODES);
    }
    h = hn;
  }

  // --- head ---  (h = B1; B0 and MEGA free)
  bgemm_k<128, 1, 0, 0, 0><<<GB_, 256, 0, stream>>>(h, nullptr, WTH1, b_h1,
      nullb, nullptr, nullptr, nullptr, nullptr, nullptr, nullptr, B0, nullptr, N_NODES);
  bgemm_k<64, 1, 0, 0, 0><<<GB_, 256, 0, stream>>>(B0, nullptr, WTH2, b_h2,
      nullb, nullptr, nullptr, nullptr, nullptr, nullptr, nullptr, MEGA, nullptr, N_NODES);
  head3_k<<<N_NODES / 4, 256, 0, stream>>>(MEGA, w_h3, b_h3, out);
}

// Round 11
// 813.330 us; speedup vs baseline: 1.0806x; 1.0525x over previous
//
#include <hip/hip_runtime.h>
#include <hip/hip_fp16.h>

typedef unsigned int uint;
typedef unsigned short ushort;
typedef __attribute__((ext_vector_type(8))) short short8;   // 8 bf16 in 4 VGPRs
typedef __attribute__((ext_vector_type(4))) float f32x4;
typedef __attribute__((ext_vector_type(2))) float f32x2;    // v_pk_fma_f32

#define N_NODES 50000
#define N_EDGES 800000
#define EREAL   (2 * N_EDGES)             // 1,600,000 staged edges
#define ETOT    (2 * N_EDGES + N_NODES)   // 1,650,000 CSR entries
#define NG      64
#define NBKT    256                       // coarse buckets (dst>>8), 196 used
#define MAXB    10240                     // EST staging capacity per bucket
#define EPB     8192                      // edges per bucket_k block
#define NBK1    ((EREAL + EPB - 1) / EPB) // 196
#define AROW    640                       // MEGA row stride in shorts (1280 B)

__device__ __forceinline__ short f2bf(float f) {   // RNE float->bf16
  uint u = __float_as_uint(f);
  u += 0x7fffu + ((u >> 16) & 1u);
  return (short)(u >> 16);
}
__device__ __forceinline__ float bf2f(short s) {
  return __uint_as_float(((uint)(ushort)s) << 16);
}
__device__ __forceinline__ uint packbf(float a, float b) {
  return (uint)(ushort)f2bf(a) | ((uint)(ushort)f2bf(b) << 16);
}
__device__ __forceinline__ uint pkh2(float a, float b) {   // 2xfp16 pack
  __half2 h = __floats2half2_rn(a, b);
  return *(uint*)&h;
}
__device__ __forceinline__ float2 uph2(uint u) {           // 2xfp16 unpack
  __half2 h = *(__half2*)&u;
  return __half22float2(h);
}

// ---------------------------------------------------------------------------
// K1: bucket REAL edges by dst>>8. LDS-staged bucket-major, then coalesced
// flush to global padded regions. Entry: src(16b) | dst(16b). Self-loops are
// NOT staged — group_k injects them. One global atomic per (block,bin).
// ---------------------------------------------------------------------------
__global__ __launch_bounds__(256) void bucket_k(const int* __restrict__ ei,
                                                int* __restrict__ gfill,
                                                uint* __restrict__ est) {
  __shared__ int hist[NBKT];
  __shared__ int scan_[NBKT];
  __shared__ int cur[NBKT];
  __shared__ int claim[NBKT];
  __shared__ int wsum[4];
  __shared__ uint stage[EPB];
  const int tid = threadIdx.x;
  hist[tid] = 0;
  __syncthreads();
  const int e0 = blockIdx.x * EPB;
  const int ecnt = min(EPB, EREAL - e0);
  // pass A: histogram
  for (int i = tid; i < ecnt; i += 256) {
    int e = e0 + i;
    int d = (e < N_EDGES) ? ei[N_EDGES + e] : ei[e - N_EDGES];
    atomicAdd(&hist[d >> 8], 1);
  }
  __syncthreads();
  // scan + global claim
  {
    int v = hist[tid];
    int lane = tid & 63, wid = tid >> 6;
    int x = v;
#pragma unroll
    for (int d = 1; d < 64; d <<= 1) {
      int t = __shfl_up(x, d, 64);
      if (lane >= d) x += t;
    }
    if (lane == 63) wsum[wid] = x;
    __syncthreads();
    int woff = 0;
#pragma unroll
    for (int j = 0; j < 4; ++j) if (j < wid) woff += wsum[j];
    scan_[tid] = woff + x - v;
    cur[tid] = woff + x - v;
    claim[tid] = atomicAdd(&gfill[tid], v);
  }
  __syncthreads();
  // pass B: stage into LDS bucket-major
  for (int i = tid; i < ecnt; i += 256) {
    int e = e0 + i;
    int s = ei[e];
    int d = (e < N_EDGES) ? ei[N_EDGES + e] : ei[e - N_EDGES];
    int p = atomicAdd(&cur[d >> 8], 1);
    stage[p] = (uint)s | ((uint)d << 16);
  }
  __syncthreads();
  // pass C: coalesced flush (consecutive p in a bucket run -> consecutive est)
  for (int p = tid; p < ecnt; p += 256) {
    uint en = stage[p];
    int b = en >> 24;                      // dst>>8 (dst < 2^16)
    int gpos = claim[b] + (p - scan_[b]);
    est[(size_t)b * MAXB + gpos] = en;
  }
}

// ---------------------------------------------------------------------------
// K2: per-bucket regroup by dst low byte -> DENSE CSR + dinv. Injects the
// self-loop (bit31-flagged) at slot 0 of every row. Dense base derived
// in-block: prefix(gfill[0..b)) + b*256 self-loops.
// ---------------------------------------------------------------------------
__global__ __launch_bounds__(256) void group_k(const int* __restrict__ gfill,
                                               const uint* __restrict__ est,
                                               const float* __restrict__ ewp,
                                               int* __restrict__ csrc,
                                               int* __restrict__ rbeg,
                                               int* __restrict__ rend,
                                               float* __restrict__ dinv) {
  __shared__ int hist[NBKT];
  __shared__ int cursor[NBKT];
  __shared__ int wsum[4];
  __shared__ int bsum[4];
  const int b = blockIdx.x;
  const int tid = threadIdx.x;
  const int lane = tid & 63, wid = tid >> 6;
  const int cnt = gfill[b];
  {
    int vv = (tid < b) ? gfill[tid] : 0;
#pragma unroll
    for (int off = 32; off; off >>= 1) vv += __shfl_xor(vv, off, 64);
    if (lane == 0) bsum[wid] = vv;
  }
  hist[tid] = 0;
  __syncthreads();
  const int gb = bsum[0] + bsum[1] + bsum[2] + bsum[3] + b * 256;  // + prior self-loops
  const uint* basep = est + (size_t)b * MAXB;
  for (int i = tid; i < cnt; i += 256)
    atomicAdd(&hist[(basep[i] >> 16) & 255], 1);
  __syncthreads();
  int v = hist[tid];
  int x = v;
#pragma unroll
  for (int d = 1; d < 64; d <<= 1) {
    int t = __shfl_up(x, d, 64);
    if (lane >= d) x += t;
  }
  if (lane == 63) wsum[wid] = x;
  __syncthreads();
  int woff = 0;
#pragma unroll
  for (int j = 0; j < 4; ++j) if (j < wid) woff += wsum[j];
  int excl = woff + x - v;                 // exclusive scan of real-edge counts
  cursor[tid] = excl + tid + 1;            // next free real slot (after self-loop)
  int node = b * 256 + tid;
  if (node < N_NODES) {
    int rs = gb + excl + tid;
    rbeg[node] = rs;
    rend[node] = rs + v + 1;
    csrc[rs] = node | (int)0x80000000;     // self-loop first, flagged
    float deg = ewp[0] * (float)v + 2.0f;
    dinv[node] = (deg > 0.f) ? rsqrtf(deg) : 0.f;
  }
  __syncthreads();
  for (int i = tid; i < cnt; i += 256) {
    uint en = basep[i];
    int dlow = (en >> 16) & 255;
    int slot = atomicAdd(&cursor[dlow], 1);
    csrc[gb + slot] = (int)(en & 0xffffu);
  }
}

// ---------------------------------------------------------------------------
// Merged prep: blocks 0..47 weight transpose, block 48 attention projection
// + bias sums, block 49 graph sizes.
// ---------------------------------------------------------------------------
__global__ __launch_bounds__(256) void prepall_k(const float* __restrict__ w_in1,
                                                 const float* __restrict__ w_in2,
                                                 const float* __restrict__ gat_w,
                                                 const float* __restrict__ gcn_w,
                                                 const float* __restrict__ skip_w,
                                                 const float* __restrict__ w_h1,
                                                 const float* __restrict__ w_h2,
                                                 const float* __restrict__ asrc,
                                                 const float* __restrict__ adst,
                                                 const float* __restrict__ gat_b,
                                                 const float* __restrict__ gcn_b,
                                                 const int* __restrict__ batch,
                                                 short* __restrict__ WT0,
                                                 short* __restrict__ WT1,
                                                 short* __restrict__ WTL2,
                                                 short* __restrict__ WTS,
                                                 short* __restrict__ WTH1,
                                                 short* __restrict__ WTH2,
                                                 short* __restrict__ ATTW,
                                                 float* __restrict__ BSUM,
                                                 int* __restrict__ gcnt) {
  __shared__ int lb[NG + 1];
  const int tid = threadIdx.x;
  if (blockIdx.x == 48) {          // attprep
    for (int t = tid; t < 3072; t += 256) {
      int l = t >> 10, rem = t & 1023;
      int r = rem >> 7, k = rem & 127;
      int hd = r & 3;
      const float* av = (r < 4) ? (asrc + l * 128 + hd * 32) : (adst + l * 128 + hd * 32);
      const float* wrow = gat_w + (size_t)l * 16384 + k * 128 + hd * 32;
      float s = 0.f;
#pragma unroll
      for (int c = 0; c < 32; ++c) s = fmaf(wrow[c], av[c], s);
      ATTW[(size_t)l * 2048 + r * 128 + k] = f2bf(s);
    }
    for (int t = tid; t < 3072; t += 256)
      ATTW[(size_t)(t >> 10) * 2048 + 1024 + (t & 1023)] = 0;
    for (int t = tid; t < 384; t += 256) {
      int l = t >> 7, c = t & 127;
      BSUM[t] = gat_b[l * 128 + c] + gcn_b[l * 128 + c];
    }
    return;
  }
  if (blockIdx.x == 49) {          // gcnt
    int g = tid;
    if (g <= NG) {
      int lo = 0, hi = N_NODES;
      while (lo < hi) {
        int mid = (lo + hi) >> 1;
        if (batch[mid] < g) lo = mid + 1; else hi = mid;
      }
      lb[g] = lo;
    }
    __syncthreads();
    if (g < NG) gcnt[g] = lb[g + 1] - lb[g];
    return;
  }
  int mat = blockIdx.x >> 2, qr = blockIdx.x & 3;
  const float* src; short* dst; int ncol = 128, dstride = 128, doff = 0;
  switch (mat) {
    case 0:  src = w_in1; dst = WT0; break;
    case 1:  src = w_in2; dst = WT1; break;
    case 2: case 3: case 4:
      src = gat_w + (size_t)(mat - 2) * 16384; dst = WTL2 + (size_t)(mat - 2) * 32768;
      dstride = 256; break;
    case 5: case 6: case 7:
      src = gcn_w + (size_t)(mat - 5) * 16384; dst = WTL2 + (size_t)(mat - 5) * 32768;
      dstride = 256; doff = 128; break;
    case 8:  src = skip_w;             dst = WTS;         break;
    case 9:  src = skip_w + 2 * 16384; dst = WTS + 16384; break;
    case 10: src = w_h1; dst = WTH1; break;
    default: src = w_h2; dst = WTH2; ncol = 64; break;
  }
  int total = 128 * ncol, chunk = total / 4;
  for (int d = qr * chunk + tid; d < (qr + 1) * chunk; d += 256) {
    int col = d >> 7, k = d & 127;
    dst[col * dstride + doff + k] = f2bf(src[k * ncol + col]);
  }
}

// ---------------------------------------------------------------------------
// bf16 MFMA GEMM (K=128). NORM: epilogue adds graphnorm+ELU of GB (fused
// normelu+skip). F32OUT -> outf (row stride NCOL).
// ---------------------------------------------------------------------------
template <int NCOL, int RELU, int F32OUT, int NORM>
__global__ __launch_bounds__(256) void bgemm_k(const short* __restrict__ A,
                                               const short* __restrict__ WT,
                                               const float* __restrict__ bias,
                                               const short* __restrict__ gb_,
                                               const int* __restrict__ batch,
                                               const int* __restrict__ gcnt,
                                               const float* __restrict__ gsum,
                                               const float* __restrict__ nw,
                                               const float* __restrict__ nb_,
                                               const float* __restrict__ nms,
                                               short* __restrict__ outb,
                                               float* __restrict__ outf, int M) {
  constexpr int NT = NCOL / 16;
  const int lane = threadIdx.x & 63;
  const int wid = threadIdx.x >> 6;
  const int mbase = blockIdx.x * 64 + wid * 16;
  const int l15 = lane & 15, q = lane >> 4;
  int arow = mbase + l15; if (arow > M - 1) arow = M - 1;
  const short* ap = A + (size_t)arow * 128 + q * 8;
  const short* bp = WT + (size_t)l15 * 128 + q * 8;
  f32x4 acc[NT];
#pragma unroll
  for (int t = 0; t < NT; ++t) acc[t] = (f32x4)0.f;
#pragma unroll
  for (int c = 0; c < 4; ++c) {
    short8 av = *(const short8*)(ap + c * 32);
#pragma unroll
    for (int t = 0; t < NT; ++t) {
      short8 bv = *(const short8*)(bp + (size_t)t * 16 * 128 + c * 32);
      acc[t] = __builtin_amdgcn_mfma_f32_16x16x32_bf16(av, bv, acc[t], 0, 0, 0);
    }
  }
#pragma unroll
  for (int t = 0; t < NT; ++t) {
    int col = t * 16 + l15;
    float bb = bias ? bias[col] : 0.f;
#pragma unroll
    for (int r = 0; r < 4; ++r) {
      int row = mbase + q * 4 + r;
      if (row < M) {
        float v = acc[t][r] + bb;
        if (NORM) {
          int b = batch[row];
          float cinv = 1.0f / fmaxf((float)gcnt[b], 1.0f);
          float mean = gsum[b * 256 + col] * cinv;
          float msq  = gsum[b * 256 + 128 + col] * cinv;
          float ms = nms[col];
          float var = fmaxf(msq - (2.0f * ms - ms * ms) * mean * mean, 0.f);
          float g = bf2f(gb_[(size_t)row * AROW + col]);
          float tn = (g - mean * ms) * rsqrtf(var + 1e-5f) * nw[col] + nb_[col];
          tn = (tn > 0.f) ? tn : (__expf(tn) - 1.0f);
          v += tn;
        }
        if (RELU) v = v > 0.f ? v : 0.f;
        if (F32OUT) outf[(size_t)row * NCOL + col] = v;
        else        outb[(size_t)row * NCOL + col] = f2bf(v);
      }
    }
  }
}

// ---------------------------------------------------------------------------
// Fused input MLP: outb = relu(x@WT0^T+b1) @ WT1^T + b2 (bf16 out).
// Intermediate staged in LDS (64x136, +8 pad -> 2-way-free banks).
// ---------------------------------------------------------------------------
__global__ __launch_bounds__(256) void mlp2_k(const float* __restrict__ x,
                                              const short* __restrict__ WT0,
                                              const float* __restrict__ b1,
                                              const short* __restrict__ WT1,
                                              const float* __restrict__ b2,
                                              short* __restrict__ outb, int M) {
  __shared__ short sh[64][136];
  const int lane = threadIdx.x & 63;
  const int wid = threadIdx.x >> 6;
  const int mbase = blockIdx.x * 64 + wid * 16;
  const int l15 = lane & 15, q = lane >> 4;
  int arow = mbase + l15; if (arow > M - 1) arow = M - 1;
  f32x4 acc[8];
#pragma unroll
  for (int t = 0; t < 8; ++t) acc[t] = (f32x4)0.f;
#pragma unroll
  for (int c = 0; c < 4; ++c) {
    const float* apf = x + (size_t)arow * 128 + q * 8 + c * 32;
    float4 fa = *(const float4*)apf;
    float4 fb = *(const float4*)(apf + 4);
    uint4 all = make_uint4(packbf(fa.x, fa.y), packbf(fa.z, fa.w),
                           packbf(fb.x, fb.y), packbf(fb.z, fb.w));
    short8 av = *(short8*)&all;
    const short* bp = WT0 + (size_t)l15 * 128 + q * 8 + c * 32;
#pragma unroll
    for (int t = 0; t < 8; ++t) {
      short8 bv = *(const short8*)(bp + (size_t)t * 16 * 128);
      acc[t] = __builtin_amdgcn_mfma_f32_16x16x32_bf16(av, bv, acc[t], 0, 0, 0);
    }
  }
#pragma unroll
  for (int t = 0; t < 8; ++t) {
    int col = t * 16 + l15;
    float bb = b1[col];
#pragma unroll
    for (int r = 0; r < 4; ++r) {
      float v = acc[t][r] + bb;
      sh[wid * 16 + q * 4 + r][col] = f2bf(v > 0.f ? v : 0.f);
    }
  }
  __syncthreads();
  f32x4 acc2[8];
#pragma unroll
  for (int t = 0; t < 8; ++t) acc2[t] = (f32x4)0.f;
  const short* ap2 = &sh[wid * 16 + l15][0] + q * 8;
#pragma unroll
  for (int c = 0; c < 4; ++c) {
    short8 av = *(const short8*)(ap2 + c * 32);
    const short* bp = WT1 + (size_t)l15 * 128 + q * 8 + c * 32;
#pragma unroll
    for (int t = 0; t < 8; ++t) {
      short8 bv = *(const short8*)(bp + (size_t)t * 16 * 128);
      acc2[t] = __builtin_amdgcn_mfma_f32_16x16x32_bf16(av, bv, acc2[t], 0, 0, 0);
    }
  }
#pragma unroll
  for (int t = 0; t < 8; ++t) {
    int col = t * 16 + l15;
    float bb = b2[col];
#pragma unroll
    for (int r = 0; r < 4; ++r) {
      int row = mbase + q * 4 + r;
      if (row < M) outb[(size_t)row * 128 + col] = f2bf(acc2[t][r] + bb);
    }
  }
}

// ---------------------------------------------------------------------------
// Fused head: out = sigmoid( relu(relu(h@W1+b1)@W2+b2) @ w3 + b3 )
// ---------------------------------------------------------------------------
__global__ __launch_bounds__(256) void head_k(const short* __restrict__ h,
                                              const short* __restrict__ WTH1,
                                              const float* __restrict__ b1,
                                              const short* __restrict__ WTH2,
                                              const float* __restrict__ b2,
                                              const float* __restrict__ w3,
                                              const float* __restrict__ b3,
                                              float* __restrict__ out, int M) {
  __shared__ short sh[64][136];
  const int lane = threadIdx.x & 63;
  const int wid = threadIdx.x >> 6;
  const int mbase = blockIdx.x * 64 + wid * 16;
  const int l15 = lane & 15, q = lane >> 4;
  int arow = mbase + l15; if (arow > M - 1) arow = M - 1;
  const short* ap = h + (size_t)arow * 128 + q * 8;
  f32x4 acc[8];
#pragma unroll
  for (int t = 0; t < 8; ++t) acc[t] = (f32x4)0.f;
#pragma unroll
  for (int c = 0; c < 4; ++c) {
    short8 av = *(const short8*)(ap + c * 32);
    const short* bp = WTH1 + (size_t)l15 * 128 + q * 8 + c * 32;
#pragma unroll
    for (int t = 0; t < 8; ++t) {
      short8 bv = *(const short8*)(bp + (size_t)t * 16 * 128);
      acc[t] = __builtin_amdgcn_mfma_f32_16x16x32_bf16(av, bv, acc[t], 0, 0, 0);
    }
  }
#pragma unroll
  for (int t = 0; t < 8; ++t) {
    int col = t * 16 + l15;
    float bb = b1[col];
#pragma unroll
    for (int r = 0; r < 4; ++r) {
      float v = acc[t][r] + bb;
      sh[wid * 16 + q * 4 + r][col] = f2bf(v > 0.f ? v : 0.f);
    }
  }
  __syncthreads();
  f32x4 p2[4];
#pragma unroll
  for (int t = 0; t < 4; ++t) p2[t] = (f32x4)0.f;
  const short* ap2 = &sh[wid * 16 + l15][0] + q * 8;
#pragma unroll
  for (int c = 0; c < 4; ++c) {
    short8 av = *(const short8*)(ap2 + c * 32);
    const short* bp = WTH2 + (size_t)l15 * 128 + q * 8 + c * 32;
#pragma unroll
    for (int t = 0; t < 4; ++t) {
      short8 bv = *(const short8*)(bp + (size_t)t * 16 * 128);
      p2[t] = __builtin_amdgcn_mfma_f32_16x16x32_bf16(av, bv, p2[t], 0, 0, 0);
    }
  }
  float w3v[4];
#pragma unroll
  for (int t = 0; t < 4; ++t) w3v[t] = w3[t * 16 + l15];
  float rsum[4];
#pragma unroll
  for (int r = 0; r < 4; ++r) {
    float s = 0.f;
#pragma unroll
    for (int t = 0; t < 4; ++t) {
      float v = p2[t][r] + b2[t * 16 + l15];
      v = v > 0.f ? v : 0.f;
      s = fmaf(v, w3v[t], s);
    }
    rsum[r] = s;
  }
#pragma unroll
  for (int off = 1; off < 16; off <<= 1)
#pragma unroll
    for (int r = 0; r < 4; ++r) rsum[r] += __shfl_xor(rsum[r], off, 64);
  if (l15 == 0) {
#pragma unroll
    for (int r = 0; r < 4; ++r) {
      int row = mbase + q * 4 + r;
      if (row < M) out[row] = 1.0f / (1.0f + __expf(-(rsum[r] + b3[0])));
    }
  }
}

// ---------------------------------------------------------------------------
// Fused coef + GAT/GCN aggregation, PER-HEAD. One node per wave. (unchanged)
// ---------------------------------------------------------------------------
__global__ __launch_bounds__(256) void agg_k(const short* __restrict__ h,
                                             const float* __restrict__ sc,
                                             const int* __restrict__ rbeg,
                                             const int* __restrict__ rend,
                                             const int* __restrict__ cs,
                                             const float* __restrict__ dinv,
                                             const float* __restrict__ ewp,
                                             short* __restrict__ A) {
  __shared__ uint4 lco[4][64];
  const int n = blockIdx.x * 4 + (threadIdx.x >> 6);
  const int wv = threadIdx.x >> 6;
  const int l = threadIdx.x & 63;
  const int sub = l >> 5;
  const int f4 = l & 31;
  const float ew0 = ewp[0];
  const float dn = dinv[n];
  const f32x4 sdv = *(const f32x4*)(sc + n * 16 + 4);
  const int beg = rbeg[n], end = rend[n];
  float den[4] = {0.f, 0.f, 0.f, 0.f};
  f32x2 ag[4][2], ac[2];
#pragma unroll
  for (int hd = 0; hd < 4; ++hd) { ag[hd][0] = (f32x2)0.f; ag[hd][1] = (f32x2)0.f; }
  ac[0] = (f32x2)0.f; ac[1] = (f32x2)0.f;

  for (int c0 = beg; c0 < end; c0 += 64) {
    const int nc = min(64, end - c0);
    {
      uint4 w = make_uint4(0u, 0u, 0u, 0u);
      int e = c0 + l;
      if (e < end) {
        int raw = cs[e];
        int s = raw & 0x7fffffff;
        float wt = (raw < 0) ? 2.0f : ew0;
        f32x4 ssv = *(const f32x4*)(sc + (size_t)s * 16);
        float a0 = ssv[0] + sdv[0]; a0 = fmaxf(a0, 0.2f * a0);
        float a1 = ssv[1] + sdv[1]; a1 = fmaxf(a1, 0.2f * a1);
        float a2 = ssv[2] + sdv[2]; a2 = fmaxf(a2, 0.2f * a2);
        float a3 = ssv[3] + sdv[3]; a3 = fmaxf(a3, 0.2f * a3);
        float e0 = __expf(a0), e1 = __expf(a1);
        float e2 = __expf(a2), e3 = __expf(a3);
        den[0] += e0; den[1] += e1; den[2] += e2; den[3] += e3;
        float c2 = dinv[s] * wt * dn;
        __half hc = __float2half(c2);
        w = make_uint4(pkh2(e0, e1), pkh2(e2, e3),
                       (uint)(*(ushort*)&hc) | ((uint)s << 16), 0u);
      }
      lco[wv][l] = w;
    }
    const int pairs = (nc + 1) & ~1;
#pragma unroll 2
    for (int j = sub; j < pairs; j += 2) {
      uint4 cw = lco[wv][j];
      int s = (int)(cw.z >> 16);
      float2 p01 = uph2(cw.x);
      float2 p23 = uph2(cw.y);
      ushort hc = (ushort)(cw.z & 0xffffu);
      float c2 = __half2float(*(__half*)&hc);
      uint2 u = *(const uint2*)(h + (size_t)s * 128 + f4 * 4);
      f32x2 va, vb;
      va.x = __uint_as_float(u.x << 16);
      va.y = __uint_as_float(u.x & 0xffff0000u);
      vb.x = __uint_as_float(u.y << 16);
      vb.y = __uint_as_float(u.y & 0xffff0000u);
      f32x2 cc;
      cc.x = p01.x; cc.y = p01.x;
      ag[0][0] += cc * va; ag[0][1] += cc * vb;
      cc.x = p01.y; cc.y = p01.y;
      ag[1][0] += cc * va; ag[1][1] += cc * vb;
      cc.x = p23.x; cc.y = p23.x;
      ag[2][0] += cc * va; ag[2][1] += cc * vb;
      cc.x = p23.y; cc.y = p23.y;
      ag[3][0] += cc * va; ag[3][1] += cc * vb;
      cc.x = c2; cc.y = c2;
      ac[0] += cc * va; ac[1] += cc * vb;
    }
  }

#pragma unroll
  for (int off = 1; off < 64; off <<= 1) {
    den[0] += __shfl_xor(den[0], off, 64);
    den[1] += __shfl_xor(den[1], off, 64);
    den[2] += __shfl_xor(den[2], off, 64);
    den[3] += __shfl_xor(den[3], off, 64);
  }
#pragma unroll
  for (int hd = 0; hd < 4; ++hd)
#pragma unroll
    for (int i = 0; i < 2; ++i) {
      f32x2 t = ag[hd][i];
      t.x += __shfl_xor(t.x, 32, 64);
      t.y += __shfl_xor(t.y, 32, 64);
      ag[hd][i] = t;
    }
#pragma unroll
  for (int i = 0; i < 2; ++i) {
    f32x2 t = ac[i];
    t.x += __shfl_xor(t.x, 32, 64);
    t.y += __shfl_xor(t.y, 32, 64);
    ac[i] = t;
  }

  float inv[4] = {1.0f / (den[0] + 1e-16f), 1.0f / (den[1] + 1e-16f),
                  1.0f / (den[2] + 1e-16f), 1.0f / (den[3] + 1e-16f)};
  short* base = A + (size_t)n * AROW;
  if (sub == 0) {
#pragma unroll
    for (int hd = 0; hd < 2; ++hd) {
      float iv = inv[hd];
      *(uint2*)(base + hd * 128 + f4 * 4) =
          make_uint2(packbf(ag[hd][0].x * iv, ag[hd][0].y * iv),
                     packbf(ag[hd][1].x * iv, ag[hd][1].y * iv));
    }
    *(uint2*)(base + 512 + f4 * 4) =
        make_uint2(packbf(ac[0].x, ac[0].y), packbf(ac[1].x, ac[1].y));
  } else {
#pragma unroll
    for (int hd = 2; hd < 4; ++hd) {
      float iv = inv[hd];
      *(uint2*)(base + hd * 128 + f4 * 4) =
          make_uint2(packbf(ag[hd][0].x * iv, ag[hd][0].y * iv),
                     packbf(ag[hd][1].x * iv, ag[hd][1].y * iv));
    }
  }
}

// ---------------------------------------------------------------------------
// Head-structured projection; GB bf16 aliases first 128 shorts of MEGA rows.
// ---------------------------------------------------------------------------
__global__ __launch_bounds__(256) void aggproj_k(const short* A,
                                                 const short* __restrict__ WT,
                                                 const float* __restrict__ bsum,
                                                 short* GB, int M) {
  const int lane = threadIdx.x & 63;
  const int wid = threadIdx.x >> 6;
  const int mbase = blockIdx.x * 64 + wid * 16;
  const int l15 = lane & 15, q = lane >> 4;
  int arow = mbase + l15; if (arow > M - 1) arow = M - 1;
  const short* ap = A + (size_t)arow * AROW + q * 8;
  const short* bp = WT + (size_t)l15 * 256 + q * 8;
  f32x4 acc[8];
#pragma unroll
  for (int t = 0; t < 8; ++t) acc[t] = (f32x4)0.f;
  short8 avg[4];
#pragma unroll
  for (int c = 0; c < 4; ++c) avg[c] = *(const short8*)(ap + 512 + c * 32);
#pragma unroll
  for (int hd = 0; hd < 4; ++hd) {
    short8 avh[4];
#pragma unroll
    for (int c = 0; c < 4; ++c) avh[c] = *(const short8*)(ap + hd * 128 + c * 32);
#pragma unroll
    for (int tt = 0; tt < 2; ++tt) {
      int t = hd * 2 + tt;
      const short* bpt = bp + (size_t)t * 16 * 256;
#pragma unroll
      for (int c = 0; c < 4; ++c) {
        short8 bv = *(const short8*)(bpt + c * 32);
        acc[t] = __builtin_amdgcn_mfma_f32_16x16x32_bf16(avh[c], bv, acc[t], 0, 0, 0);
      }
#pragma unroll
      for (int c = 0; c < 4; ++c) {
        short8 bv = *(const short8*)(bpt + 128 + c * 32);
        acc[t] = __builtin_amdgcn_mfma_f32_16x16x32_bf16(avg[c], bv, acc[t], 0, 0, 0);
      }
    }
  }
#pragma unroll
  for (int t = 0; t < 8; ++t) {
    int col = t * 16 + l15;
    float bb = bsum[col];
#pragma unroll
    for (int r = 0; r < 4; ++r) {
      int row = mbase + q * 4 + r;
      if (row < M) GB[(size_t)row * AROW + col] = f2bf(acc[t][r] + bb);
    }
  }
}

// ---------------------------------------------------------------------------
// GraphNorm stats on GB (bf16, row stride AROW).
// ---------------------------------------------------------------------------
__global__ __launch_bounds__(256) void stats_k(const short* __restrict__ gb,
                                               const int* __restrict__ batch,
                                               float* __restrict__ gsum) {
  int c2 = threadIdx.x & 63;
  int qr = threadIdx.x >> 6;
  int nb = blockIdx.x * 16;
  float s0 = 0.f, s1 = 0.f, q0 = 0.f, q1 = 0.f;
  int curb = -1;
  for (int i = qr; i < 16; i += 4) {
    int n = nb + i;
    int b = batch[n];
    if (b != curb) {
      if (curb >= 0) {
        atomicAdd(&gsum[curb * 256 + 2 * c2], s0);
        atomicAdd(&gsum[curb * 256 + 2 * c2 + 1], s1);
        atomicAdd(&gsum[curb * 256 + 128 + 2 * c2], q0);
        atomicAdd(&gsum[curb * 256 + 128 + 2 * c2 + 1], q1);
      }
      curb = b; s0 = s1 = q0 = q1 = 0.f;
    }
    uint u = *(const uint*)(gb + (size_t)n * AROW + 2 * c2);
    float v0 = __uint_as_float(u << 16);
    float v1 = __uint_as_float(u & 0xffff0000u);
    s0 += v0; q0 = fmaf(v0, v0, q0);
    s1 += v1; q1 = fmaf(v1, v1, q1);
  }
  if (curb >= 0) {
    atomicAdd(&gsum[curb * 256 + 2 * c2], s0);
    atomicAdd(&gsum[curb * 256 + 2 * c2 + 1], s1);
    atomicAdd(&gsum[curb * 256 + 128 + 2 * c2], q0);
    atomicAdd(&gsum[curb * 256 + 128 + 2 * c2 + 1], q1);
  }
}

// GraphNorm + ELU: GB bf16 (stride AROW) -> outb bf16 (stride 128). Layer 1.
__global__ __launch_bounds__(256) void normelu_k(const short* __restrict__ gb,
                                                 const int* __restrict__ batch,
                                                 const float* __restrict__ gsum,
                                                 const int* __restrict__ gcnt,
                                                 const float* __restrict__ nw,
                                                 const float* __restrict__ nb_,
                                                 const float* __restrict__ nms,
                                                 short* __restrict__ outb) {
  int n = blockIdx.x * 4 + (threadIdx.x >> 6);
  int c2 = threadIdx.x & 63;
  int b = batch[n];
  float cntf = fmaxf((float)gcnt[b], 1.0f);
  float cinv = 1.0f / cntf;
  uint u = *(const uint*)(gb + (size_t)n * AROW + 2 * c2);
  float o[2];
#pragma unroll
  for (int k = 0; k < 2; ++k) {
    int c = 2 * c2 + k;
    float mean = gsum[b * 256 + c] * cinv;
    float msq  = gsum[b * 256 + 128 + c] * cinv;
    float ms = nms[c];
    float var = fmaxf(msq - (2.0f * ms - ms * ms) * mean * mean, 0.f);
    float v = (k == 0) ? __uint_as_float(u << 16) : __uint_as_float(u & 0xffff0000u);
    float t = (v - mean * ms) * rsqrtf(var + 1e-5f) * nw[c] + nb_[c];
    o[k] = (t > 0.f) ? t : (__expf(t) - 1.0f);
  }
  *(uint*)(outb + (size_t)n * 128 + 2 * c2) = packbf(o[0], o[1]);
}

// ---------------------------------------------------------------------------
extern "C" void kernel_launch(void* const* d_in, const int* in_sizes, int n_in,
                              void* d_out, int out_size, void* d_ws, size_t ws_size,
                              hipStream_t stream) {
  const float* x      = (const float*)d_in[0];
  const int*   ei     = (const int*)d_in[1];
  const int*   batch  = (const int*)d_in[2];
  const float* w_in1  = (const float*)d_in[3];
  const float* b_in1  = (const float*)d_in[4];
  const float* w_in2  = (const float*)d_in[5];
  const float* b_in2  = (const float*)d_in[6];
  const float* gat_w  = (const float*)d_in[7];
  const float* gat_as = (const float*)d_in[8];
  const float* gat_ad = (const float*)d_in[9];
  const float* gat_b  = (const float*)d_in[10];
  const float* gcn_w  = (const float*)d_in[11];
  const float* gcn_b  = (const float*)d_in[12];
  const float* norm_w = (const float*)d_in[13];
  const float* norm_b = (const float*)d_in[14];
  const float* norm_ms= (const float*)d_in[15];
  const float* skip_w = (const float*)d_in[16];
  const float* skip_b = (const float*)d_in[17];
  const float* w_h1   = (const float*)d_in[18];
  const float* b_h1   = (const float*)d_in[19];
  const float* w_h2   = (const float*)d_in[20];
  const float* b_h2   = (const float*)d_in[21];
  const float* w_h3   = (const float*)d_in[22];
  const float* b_h3   = (const float*)d_in[23];
  const float* ewp    = (const float*)d_in[24];
  float* out = (float*)d_out;

  // Workspace (~101 MB). MEGA holds A [N][640] bf16; GB aliases first 128
  // shorts of each A row; EST staging aliases MEGA too.
  char* p = (char*)d_ws;
  const size_t NBH = (size_t)N_NODES * 128 * sizeof(short);  // 12.8 MB
  short* B0   = (short*)p; p += NBH;
  short* B1   = (short*)p; p += NBH;
  short* MEGA = (short*)p; p += (size_t)N_NODES * AROW * sizeof(short);  // 64 MB
  short* GB   = MEGA;
  uint*  EST  = (uint*)MEGA;
  float* SC   = (float*)p; p += (size_t)N_NODES * 16 * sizeof(float);
  int*   CSRC = (int*)p;   p += (size_t)ETOT * sizeof(int);   // dense 6.6 MB
  int*   RBEG = (int*)p;   p += (size_t)N_NODES * sizeof(int);
  int*   REND = (int*)p;   p += (size_t)N_NODES * sizeof(int);
  char*  zbase = p;
  int*   GFILL= (int*)p;   p += (size_t)NBKT * sizeof(int);
  float* GSUM = (float*)p; p += (size_t)3 * NG * 256 * sizeof(float);
  size_t znb  = (size_t)((char*)p - zbase);
  int*   GCNT = (int*)p;   p += (size_t)NG * sizeof(int);
  float* DINV = (float*)p; p += (size_t)N_NODES * sizeof(float);
  short* WT0  = (short*)p; p += 16384 * sizeof(short);
  short* WT1  = (short*)p; p += 16384 * sizeof(short);
  short* WTL2 = (short*)p; p += 3 * 32768 * sizeof(short);   // [gat;gcn] K=256
  short* WTS  = (short*)p; p += 2 * 16384 * sizeof(short);
  short* WTH1 = (short*)p; p += 16384 * sizeof(short);
  short* WTH2 = (short*)p; p += 8192 * sizeof(short);
  short* ATTW = (short*)p; p += 3 * 2048 * sizeof(short);    // [l][16][128]
  float* BSUM = (float*)p; p += 3 * 128 * sizeof(float);

  const int GB_ = (N_NODES + 63) / 64;    // 782 gemm blocks
  const short* nullb = nullptr;

  // --- CSR build + prep ---
  hipMemsetAsync(zbase, 0, znb, stream);
  bucket_k<<<NBK1, 256, 0, stream>>>(ei, GFILL, EST);
  group_k<<<196, 256, 0, stream>>>(GFILL, EST, ewp, CSRC, RBEG, REND, DINV);
  prepall_k<<<50, 256, 0, stream>>>(w_in1, w_in2, gat_w, gcn_w, skip_w, w_h1,
                                    w_h2, gat_as, gat_ad, gat_b, gcn_b, batch,
                                    WT0, WT1, WTL2, WTS, WTH1, WTH2, ATTW,
                                    BSUM, GCNT);

  // --- input MLP fused: x(fp32) -> B0 (h0) ---
  mlp2_k<<<GB_, 256, 0, stream>>>(x, WT0, b_in1, WT1, b_in2, B0, N_NODES);

  short* h = B0;
  for (int i = 0; i < 3; ++i) {
    short* hn = (h == B0) ? B1 : B0;
    float* gsum_i = GSUM + (size_t)i * NG * 256;
    const float* nw  = norm_w  + (size_t)i * 128;
    const float* nb  = norm_b  + (size_t)i * 128;
    const float* nms = norm_ms + (size_t)i * 128;
    // scores: SC[N,16] = h @ ATTW^T (cols 0-3 src, 4-7 dst per head)
    bgemm_k<16, 0, 1, 0><<<GB_, 256, 0, stream>>>(h, ATTW + (size_t)i * 2048,
        nullptr, nullb, nullptr, nullptr, nullptr, nullptr, nullptr, nullptr,
        nullptr, SC, N_NODES);
    agg_k<<<N_NODES / 4, 256, 0, stream>>>(h, SC, RBEG, REND, CSRC, DINV, ewp, MEGA);
    aggproj_k<<<GB_, 256, 0, stream>>>(MEGA, WTL2 + (size_t)i * 32768,
                                       BSUM + i * 128, GB, N_NODES);
    stats_k<<<N_NODES / 16, 256, 0, stream>>>(GB, batch, gsum_i);
    if (i == 1) {
      normelu_k<<<N_NODES / 4, 256, 0, stream>>>(GB, batch, gsum_i, GCNT,
                                                 nw, nb, nms, hn);
    } else {
      // hn = normelu(GB) + h @ skip_w + skip_b   (fused epilogue)
      const short* wts = WTS + (size_t)(i == 0 ? 0 : 1) * 16384;
      bgemm_k<128, 0, 0, 1><<<GB_, 256, 0, stream>>>(h, wts,
          skip_b + (size_t)i * 128, GB, batch, GCNT, gsum_i, nw, nb, nms,
          hn, nullptr, N_NODES);
    }
    h = hn;
  }

  // --- fused head ---  (h = B1)
  head_k<<<GB_, 256, 0, stream>>>(h, WTH1, b_h1, WTH2, b_h2, w_h3, b_h3, out,
                                  N_NODES);
}